// Round 2
// baseline (15547.455 us; speedup 1.0000x reference)
//
#include <hip/hip_runtime.h>
#include <math.h>

#define S_   256
#define B_   32
#define H_   512
#define E_   256
#define V_   10000
#define K_   3
#define T_   32
#define N1_  96
#define BOS_ 1
#define EOS_ 1
#define NEG_ (-1000000000.0f)
#define RT   4        // per-row top-RT kept for exact beam merge (RT > K suffices)
#define LG_MT 79      // ceil(10000/128) m-tiles in logits GEMM
#define GST  (N1_ * 4 * H_)   // gts part stride (floats)

// ---------------------------------------------------------------------------
// Generic fp32 tiled GEMM — used for the 3 prologue GEMMs only (unchanged).
// ---------------------------------------------------------------------------
__global__ __launch_bounds__(256) void gemm_k(
    const float* __restrict__ A, const float* __restrict__ B1,
    const float* __restrict__ B2, int split,
    const float* __restrict__ bias1, const float* __restrict__ bias2,
    float* __restrict__ C, int N, int Kd, int M, int klen, size_t cstride)
{
  __shared__ float As[16][64];
  __shared__ float Bs[16][64];
  const int tid = threadIdx.x;
  const int m0 = blockIdx.x * 64;
  const int n0 = blockIdx.y * 64;
  const int kstart = blockIdx.z * klen;
  const int kend = kstart + klen;
  const int tm = tid & 15, tn = tid >> 4;
  const int la_n = tid & 63;
  const int la_k = (tid >> 6) * 4;
  const int lb_m = (tid & 15) * 4;
  const int lb_k = tid >> 4;

  const int an = (n0 + la_n < N) ? (n0 + la_n) : 0;   // clamp (store guarded)
  const float* Arow = A + (size_t)an * Kd;
  float* Cpart = C + (size_t)blockIdx.z * cstride;

  float4 a_reg, b_reg;
  a_reg = *(const float4*)(Arow + kstart + la_k);
  {
    int krow = kstart + lb_k;
    const float* Brow = (krow < split) ? (B1 + (size_t)krow * M)
                                       : (B2 + (size_t)(krow - split) * M);
    int m = m0 + lb_m;
    if (m + 3 < M) b_reg = *(const float4*)(Brow + m);
    else {
      b_reg.x = (m + 0 < M) ? Brow[m + 0] : 0.f;
      b_reg.y = (m + 1 < M) ? Brow[m + 1] : 0.f;
      b_reg.z = (m + 2 < M) ? Brow[m + 2] : 0.f;
      b_reg.w = (m + 3 < M) ? Brow[m + 3] : 0.f;
    }
  }

  float acc[4][4] = {};

  for (int k0 = kstart; k0 < kend; k0 += 16) {
    if (k0 > kstart) __syncthreads();
    As[la_k + 0][la_n] = a_reg.x; As[la_k + 1][la_n] = a_reg.y;
    As[la_k + 2][la_n] = a_reg.z; As[la_k + 3][la_n] = a_reg.w;
    *(float4*)&Bs[lb_k][lb_m] = b_reg;
    __syncthreads();
    if (k0 + 16 < kend) {
      a_reg = *(const float4*)(Arow + (k0 + 16) + la_k);
      int krow = k0 + 16 + lb_k;
      const float* Brow = (krow < split) ? (B1 + (size_t)krow * M)
                                         : (B2 + (size_t)(krow - split) * M);
      int m = m0 + lb_m;
      if (m + 3 < M) b_reg = *(const float4*)(Brow + m);
      else {
        b_reg.x = (m + 0 < M) ? Brow[m + 0] : 0.f;
        b_reg.y = (m + 1 < M) ? Brow[m + 1] : 0.f;
        b_reg.z = (m + 2 < M) ? Brow[m + 2] : 0.f;
        b_reg.w = (m + 3 < M) ? Brow[m + 3] : 0.f;
      }
    }
#pragma unroll
    for (int kk = 0; kk < 16; kk++) {
      float4 av = *(const float4*)&As[kk][tn * 4];
      float4 bv = *(const float4*)&Bs[kk][tm * 4];
      float a[4] = {av.x, av.y, av.z, av.w};
      float b[4] = {bv.x, bv.y, bv.z, bv.w};
#pragma unroll
      for (int i = 0; i < 4; i++)
#pragma unroll
        for (int j = 0; j < 4; j++) acc[i][j] += a[i] * b[j];
    }
  }

  const bool addBias = (blockIdx.z == 0);
#pragma unroll
  for (int i = 0; i < 4; i++) {
    int n = n0 + tn * 4 + i;
    if (n >= N) continue;
#pragma unroll
    for (int j = 0; j < 4; j++) {
      int m = m0 + tm * 4 + j;
      if (m >= M) continue;
      float v = acc[i][j];
      if (addBias && bias1) v += bias1[m];
      if (addBias && bias2) v += bias2[m];
      Cpart[(size_t)n * M + m] = v;
    }
  }
}

// ---- top-k helpers (jax tie-break: value desc, then smaller index) ----
__device__ __forceinline__ bool tk_better(float va, int ia, float vb, int ib) {
  return (va > vb) || (va == vb && ia < ib);
}
__device__ __forceinline__ void tk_insertN(float v, int i, float* vv, int* ii) {
  if (!tk_better(v, i, vv[RT - 1], ii[RT - 1])) return;
  vv[RT - 1] = v; ii[RT - 1] = i;
#pragma unroll
  for (int q = RT - 1; q > 0; q--) {
    if (tk_better(vv[q], ii[q], vv[q - 1], ii[q - 1])) {
      float tv = vv[q]; vv[q] = vv[q - 1]; vv[q - 1] = tv;
      int ti = ii[q]; ii[q] = ii[q - 1]; ii[q - 1] = ti;
    }
  }
}
// merge sorted list (bv2,bi2) into (av,ai), keep RT best
__device__ __forceinline__ void tk_merge_reg(float* av, int* ai,
                                             const float* bv2, const int* bi2) {
  float rv[RT]; int ri[RT];
  int p = 0, q = 0;
#pragma unroll
  for (int t = 0; t < RT; t++) {
    bool ta;
    if (p >= RT) ta = false;
    else if (q >= RT) ta = true;
    else ta = tk_better(av[p], ai[p], bv2[q], bi2[q]);
    if (ta) { rv[t] = av[p]; ri[t] = ai[p]; p++; }
    else    { rv[t] = bv2[q]; ri[t] = bi2[q]; q++; }
  }
#pragma unroll
  for (int t = 0; t < RT; t++) { av[t] = rv[t]; ai[t] = ri[t]; }
}
// LDS pairwise merge
__device__ __forceinline__ void tk_merge_lds(float* sv, int* si, int a, int b) {
  float rv[RT]; int ri[RT];
  int p = 0, q = 0;
#pragma unroll
  for (int t = 0; t < RT; t++) {
    bool ta;
    if (p >= RT) ta = false;
    else if (q >= RT) ta = true;
    else ta = tk_better(sv[a + p], si[a + p], sv[b + q], si[b + q]);
    if (ta) { rv[t] = sv[a + p]; ri[t] = si[a + p]; p++; }
    else    { rv[t] = sv[b + q]; ri[t] = si[b + q]; q++; }
  }
#pragma unroll
  for (int t = 0; t < RT; t++) { sv[a + t] = rv[t]; si[a + t] = ri[t]; }
}

__device__ __forceinline__ float sigf(float x) { return 1.f / (1.f + expf(-x)); }

// ---------------------------------------------------------------------------
// merge of LG_MT per-tile partials for one row -> top-RT + max + lse (in LDS).
// Called by all 256 threads of a block. Ends with __syncthreads().
// ---------------------------------------------------------------------------
__device__ void merge_row_dev(int n, int tid,
    const float* __restrict__ ptv, const int* __restrict__ pti,
    const float* __restrict__ pmx, const float* __restrict__ psm,
    float* msv, int* msi, float* mred,
    float* outv, int* outi, float* outM, float* outL)
{
  float mx_t = -3.4e38f, sm_t = 0.f;
  if (tid < 128) {
    float vv[RT]; int ii[RT];
#pragma unroll
    for (int q = 0; q < RT; q++) { vv[q] = -3.4e38f; ii[q] = 0x7fffffff; }
    if (tid < LG_MT) {
      const size_t pb = (size_t)n * LG_MT + tid;
#pragma unroll
      for (int q = 0; q < RT; q++) { vv[q] = ptv[pb * RT + q]; ii[q] = pti[pb * RT + q]; }
      mx_t = pmx[pb]; sm_t = psm[pb];
    }
#pragma unroll
    for (int q = 0; q < RT; q++) { msv[tid * RT + q] = vv[q]; msi[tid * RT + q] = ii[q]; }
  }
  __syncthreads();
  for (int st = 64; st; st >>= 1) {
    if (tid < st) tk_merge_lds(msv, msi, tid * RT, (tid + st) * RT);
    __syncthreads();
  }
  if (tid < 128) mred[tid] = mx_t;
  __syncthreads();
  for (int st = 64; st; st >>= 1) {
    if (tid < st) mred[tid] = fmaxf(mred[tid], mred[tid + st]);
    __syncthreads();
  }
  const float Mg = mred[0];
  __syncthreads();
  if (tid < 128) mred[tid] = sm_t * expf(mx_t - Mg);
  __syncthreads();
  for (int st = 64; st; st >>= 1) {
    if (tid < st) mred[tid] += mred[tid + st];
    __syncthreads();
  }
  if (tid == 0) {
    *outM = Mg; *outL = logf(mred[0]);
#pragma unroll
    for (int q = 0; q < RT; q++) { outv[q] = msv[q]; outi[q] = msi[q]; }
  }
  __syncthreads();
}

// ---------------------------------------------------------------------------
// Persistent decode kernel params
// ---------------------------------------------------------------------------
struct DK {
  const float *enc, *mask, *emb, *Wp, *Wv, *W_ih, *W_hh, *b_ih, *b_hh, *Wc, *bc;
  const float *encp;
  float *h, *c, *h2, *c2, *xcat, *gts;
  float *ptv, *pmx, *psm, *cumA, *cumB;
  int *pti, *tok, *eosA, *eosB, *pA, *pB;
  float *out;
  unsigned *bar;
};

// device-wide barrier: monotonic counter, relaxed spin + fence. Timeout escape
// (~20ms @ 100MHz realtime clock) turns a residency failure into a wrong
// answer instead of a GPU hang.
__device__ __forceinline__ void gbar(unsigned* bar, unsigned* pcalls) {
  __syncthreads();
  if (threadIdx.x == 0) {
    const unsigned tgt = (++(*pcalls)) * (unsigned)gridDim.x;
    __hip_atomic_fetch_add(bar, 1u, __ATOMIC_ACQ_REL, __HIP_MEMORY_SCOPE_AGENT);
    const long long t0 = (long long)__builtin_amdgcn_s_memrealtime();
    while (__hip_atomic_load(bar, __ATOMIC_RELAXED, __HIP_MEMORY_SCOPE_AGENT) < tgt) {
      __builtin_amdgcn_s_sleep(8);
      if ((long long)__builtin_amdgcn_s_memrealtime() - t0 > 2000000LL) break;
    }
    __threadfence();   // acquire: invalidate caches so we see other XCDs' writes
  }
  __syncthreads();
}

// ---------------------------------------------------------------------------
// One persistent kernel for the whole T=32 decode loop. Grid size is chosen
// host-side from the occupancy API (<= co-resident capacity, <= 256). Every
// phase is a grid-stride loop over its job count, so ANY grid size is correct.
// 5 device barriers per step: attn | gates GEMM | LSTM | logits GEMM | reorder.
// Phase bodies are verbatim ports of the verified multi-kernel version,
// preserving summation orders and tie-breaking exactly.
// ---------------------------------------------------------------------------
__global__ __launch_bounds__(256) void decode_k(DK P)
{
  const int bid = blockIdx.x;
  const int nblk = gridDim.x;
  const int tid = threadIdx.x;
  unsigned calls = 0;

  __shared__ float gAs[16][64];   // gates GEMM
  __shared__ float gBs[16][64];
  __shared__ float lAs[16][32];   // logits GEMM
  __shared__ float lBs[16][128];
  __shared__ float hS[512];       // attention phase
  __shared__ float ppS[512];
  __shared__ float WvS[512];
  __shared__ float scS[256];
  __shared__ float red[256];
  __shared__ float msv[128 * RT]; // merge phase
  __shared__ int   msi[128 * RT];
  __shared__ float mred[128];
  __shared__ float rmv[K_][RT];
  __shared__ int   rmi[K_][RT];
  __shared__ float rM[K_], rL[K_];
  __shared__ float s_val[K_];
  __shared__ int   s_g[K_], s_tok[K_];

  for (int t = 0; t < T_; t++) {
    const int N = (t == 0) ? B_ : N1_;

    // ================= phase A: attention (pp + scores + softmax + ctx) ====
    for (int n = bid; n < N; n += nblk) {
      __syncthreads();   // LDS reuse guard between job iterations
      const int b = (t == 0) ? n : (n / K_);
      float* xr = P.xcat + (size_t)n * 1280;

      const float hv0 = P.h[(size_t)n * H_ + tid];
      const float hv1 = P.h[(size_t)n * H_ + 256 + tid];
      hS[tid] = hv0; hS[256 + tid] = hv1;
      WvS[tid] = P.Wv[tid]; WvS[256 + tid] = P.Wv[256 + tid];
      xr[E_ + H_ + tid] = hv0;                 // hprev
      xr[E_ + H_ + 256 + tid] = hv1;
      {
        const int tk = (t == 0) ? BOS_ : P.tok[n];
        xr[tid] = P.emb[(size_t)tk * E_ + tid];  // ex (tid spans 0..255 == E_)
      }
      __syncthreads();

      // pp = h @ Wp — 4 k-chunks of 128, combined left-assoc (matches old
      // ppgemv's kg-group partials + red[tid]+red[64+tid]+... order).
      {
        float p00 = 0.f, p01 = 0.f, p02 = 0.f, p03 = 0.f;
        float p10 = 0.f, p11 = 0.f, p12 = 0.f, p13 = 0.f;
#pragma unroll 4
        for (int kk = 0; kk < 128; kk++) {
          const float h0 = hS[kk], h1 = hS[128 + kk];
          const float h2v = hS[256 + kk], h3 = hS[384 + kk];
          const float* wr0 = P.Wp + (size_t)kk * H_;
          const float* wr1 = P.Wp + (size_t)(128 + kk) * H_;
          const float* wr2 = P.Wp + (size_t)(256 + kk) * H_;
          const float* wr3 = P.Wp + (size_t)(384 + kk) * H_;
          p00 += h0 * wr0[tid];        p01 += h1 * wr1[tid];
          p02 += h2v * wr2[tid];       p03 += h3 * wr3[tid];
          p10 += h0 * wr0[256 + tid];  p11 += h1 * wr1[256 + tid];
          p12 += h2v * wr2[256 + tid]; p13 += h3 * wr3[256 + tid];
        }
        ppS[tid] = p00 + p01 + p02 + p03;
        ppS[256 + tid] = p10 + p11 + p12 + p13;
      }
      __syncthreads();

      // scores (one warp per s mod 4) — identical math to old score_k
      {
        const int w = tid >> 6, lane = tid & 63;
        for (int s = w; s < S_; s += 4) {
          const float* ep = P.encp + ((size_t)s * B_ + b) * H_;
          float acc = 0.f;
#pragma unroll
          for (int r = 0; r < 8; r++) {
            const int hh = r * 64 + lane;
            acc += tanhf(ppS[hh] + ep[hh]) * WvS[hh];
          }
#pragma unroll
          for (int off = 32; off; off >>= 1) acc += __shfl_xor(acc, off);
          if (lane == 0)
            scS[s] = (P.mask[(size_t)b * S_ + s] == 0.f) ? NEG_ : acc;
        }
      }
      __syncthreads();

      // softmax (same pairwise trees as old ctx_k)
      float v = scS[tid];
      red[tid] = v; __syncthreads();
      for (int st = 128; st; st >>= 1) {
        if (tid < st) red[tid] = fmaxf(red[tid], red[tid + st]);
        __syncthreads();
      }
      const float mx = red[0]; __syncthreads();
      const float e = expf(v - mx);
      scS[tid] = e;
      red[tid] = e; __syncthreads();
      for (int st = 128; st; st >>= 1) {
        if (tid < st) red[tid] += red[tid + st];
        __syncthreads();
      }
      const float rsum = 1.f / red[0];
      __syncthreads();

      // ctx — 4 s-phase partials per col, combined left-assoc (matches old
      // ctx_k's sgrp partials + red[tid]+red[64+tid]+... order).
      {
        float c00 = 0.f, c01 = 0.f, c02 = 0.f, c03 = 0.f;
        float c10 = 0.f, c11 = 0.f, c12 = 0.f, c13 = 0.f;
#pragma unroll 2
        for (int s0 = 0; s0 < S_; s0 += 4) {
          const float a0 = scS[s0 + 0], a1 = scS[s0 + 1];
          const float a2 = scS[s0 + 2], a3 = scS[s0 + 3];
          const float* e0 = P.enc + ((size_t)(s0 + 0) * B_ + b) * H_;
          const float* e1 = P.enc + ((size_t)(s0 + 1) * B_ + b) * H_;
          const float* e2 = P.enc + ((size_t)(s0 + 2) * B_ + b) * H_;
          const float* e3 = P.enc + ((size_t)(s0 + 3) * B_ + b) * H_;
          c00 += a0 * e0[tid];       c01 += a1 * e1[tid];
          c02 += a2 * e2[tid];       c03 += a3 * e3[tid];
          c10 += a0 * e0[256 + tid]; c11 += a1 * e1[256 + tid];
          c12 += a2 * e2[256 + tid]; c13 += a3 * e3[256 + tid];
        }
        xr[E_ + tid] = (c00 + c01 + c02 + c03) * rsum;
        xr[E_ + 256 + tid] = (c10 + c11 + c12 + c13) * rsum;
      }
    }
    gbar(P.bar, &calls);

    // ================= phase B: gates GEMM (64x64 tiles, split-K 4) ========
    {
      const int ntiles = (t == 0) ? 1 : 2;
      const int jobs = 32 * ntiles * 4;
      for (int job = bid; job < jobs; job += nblk) {
        __syncthreads();   // LDS reuse guard
        const int bx = job & 31;
        const int rem = job >> 5;
        const int by = rem % ntiles;
        const int bz = rem / ntiles;
        const int m0 = bx * 64;
        const int n0 = by * 64;
        const int kstart = bz * 320;
        const int kend = kstart + 320;
        const int tm = tid & 15, tn = tid >> 4;
        const int la_n = tid & 63;
        const int la_k = (tid >> 6) * 4;
        const int lb_m = (tid & 15) * 4;
        const int lb_k = tid >> 4;
        const int an = (n0 + la_n < N) ? (n0 + la_n) : 0;
        const float* Arow = P.xcat + (size_t)an * 1280;
        float* Cpart = P.gts + (size_t)bz * GST;

        float4 a_reg = *(const float4*)(Arow + kstart + la_k);
        float4 b_reg;
        {
          const int krow = kstart + lb_k;
          const float* Brow = (krow < 768) ? (P.W_ih + (size_t)krow * 2048)
                                           : (P.W_hh + (size_t)(krow - 768) * 2048);
          b_reg = *(const float4*)(Brow + m0 + lb_m);   // M=2048, no edge
        }
        float acc[4][4] = {};
        for (int k0 = kstart; k0 < kend; k0 += 16) {
          if (k0 > kstart) __syncthreads();
          gAs[la_k + 0][la_n] = a_reg.x; gAs[la_k + 1][la_n] = a_reg.y;
          gAs[la_k + 2][la_n] = a_reg.z; gAs[la_k + 3][la_n] = a_reg.w;
          *(float4*)&gBs[lb_k][lb_m] = b_reg;
          __syncthreads();
          if (k0 + 16 < kend) {
            a_reg = *(const float4*)(Arow + (k0 + 16) + la_k);
            const int krow = k0 + 16 + lb_k;
            const float* Brow = (krow < 768) ? (P.W_ih + (size_t)krow * 2048)
                                             : (P.W_hh + (size_t)(krow - 768) * 2048);
            b_reg = *(const float4*)(Brow + m0 + lb_m);
          }
#pragma unroll
          for (int kk = 0; kk < 16; kk++) {
            float4 av = *(const float4*)&gAs[kk][tn * 4];
            float4 bv = *(const float4*)&gBs[kk][tm * 4];
            float a[4] = {av.x, av.y, av.z, av.w};
            float b[4] = {bv.x, bv.y, bv.z, bv.w};
#pragma unroll
            for (int i = 0; i < 4; i++)
#pragma unroll
              for (int j = 0; j < 4; j++) acc[i][j] += a[i] * b[j];
          }
        }
        const bool addBias = (bz == 0);
#pragma unroll
        for (int i = 0; i < 4; i++) {
          const int n = n0 + tn * 4 + i;
          if (n >= N) continue;
#pragma unroll
          for (int j = 0; j < 4; j++) {
            const int m = m0 + tm * 4 + j;
            float vv = acc[i][j];
            if (addBias) { vv += P.b_ih[m]; vv += P.b_hh[m]; }
            Cpart[(size_t)n * 2048 + m] = vv;
          }
        }
      }
    }
    gbar(P.bar, &calls);

    // ================= phase C: LSTM pointwise =============================
    for (int n = bid; n < N; n += nblk) {
      float* xr = P.xcat + (size_t)n * 1280;
      for (int i = tid; i < H_; i += 256) {
        float gi = 0.f, gf = 0.f, gg = 0.f, go = 0.f;
#pragma unroll
        for (int p = 0; p < 4; p++) {
          const float* g = P.gts + (size_t)p * GST + (size_t)n * (4 * H_);
          gi += g[i]; gf += g[H_ + i]; gg += g[2 * H_ + i]; go += g[3 * H_ + i];
        }
        const float ctx_i = xr[E_ + i];
        const float cc = P.c[(size_t)n * H_ + i];
        const float cv = sigf(gf) * cc + sigf(gi) * tanhf(gg);
        const float hv = sigf(go) * tanhf(cv);
        P.c2[(size_t)n * H_ + i] = cv;
        P.h2[(size_t)n * H_ + i] = hv;
        xr[E_ + i] = hv;
        xr[E_ + H_ + i] = ctx_i;
      }
    }
    gbar(P.bar, &calls);

    // ================= phase D: logits GEMM + fused top-RT epilogue ========
    {
      const int nt32 = (t == 0) ? 1 : 3;
      const int jobs = LG_MT * nt32;
      for (int job = bid; job < jobs; job += nblk) {
        __syncthreads();   // LDS reuse guard
        const int mt = job % LG_MT;
        const int nb2 = job / LG_MT;
        const int m0 = mt * 128;
        const int n0 = nb2 * 32;
        const int tm = tid & 31;
        const int tn = tid >> 5;
        const bool aload = tid < 128;
        const int ar = tid & 31;
        const int ak = ((tid >> 5) & 3) * 4;
        const int arow_idx = (n0 + ar < N) ? (n0 + ar) : 0;
        const float* Arow = P.xcat + (size_t)arow_idx * 1280;
        const bool edge = (m0 + 128 > V_);

        float4 a_reg = make_float4(0.f, 0.f, 0.f, 0.f);
        float4 b_reg[2];
        if (aload) a_reg = *(const float4*)(Arow + ak);
#pragma unroll
        for (int l = 0; l < 2; l++) {
          const int idx = l * 256 + tid;
          const int kr = idx >> 5, c4 = (idx & 31) * 4;
          const float* Brow = P.Wc + (size_t)kr * V_;
          if (!edge) b_reg[l] = *(const float4*)(Brow + m0 + c4);
          else {
            float4 bv;
            bv.x = (m0 + c4 + 0 < V_) ? Brow[m0 + c4 + 0] : 0.f;
            bv.y = (m0 + c4 + 1 < V_) ? Brow[m0 + c4 + 1] : 0.f;
            bv.z = (m0 + c4 + 2 < V_) ? Brow[m0 + c4 + 2] : 0.f;
            bv.w = (m0 + c4 + 3 < V_) ? Brow[m0 + c4 + 3] : 0.f;
            b_reg[l] = bv;
          }
        }

        float acc[4][4] = {};
        for (int k0 = 0; k0 < 1280; k0 += 16) {
          if (k0 > 0) __syncthreads();
          if (aload) {
            lAs[ak + 0][ar] = a_reg.x; lAs[ak + 1][ar] = a_reg.y;
            lAs[ak + 2][ar] = a_reg.z; lAs[ak + 3][ar] = a_reg.w;
          }
#pragma unroll
          for (int l = 0; l < 2; l++) {
            const int idx = l * 256 + tid;
            const int kr = idx >> 5, c4 = (idx & 31) * 4;
            *(float4*)&lBs[kr][c4] = b_reg[l];
          }
          __syncthreads();
          if (k0 + 16 < 1280) {
            if (aload) a_reg = *(const float4*)(Arow + (k0 + 16) + ak);
#pragma unroll
            for (int l = 0; l < 2; l++) {
              const int idx = l * 256 + tid;
              const int kr = k0 + 16 + (idx >> 5), c4 = (idx & 31) * 4;
              const float* Brow = P.Wc + (size_t)kr * V_;
              if (!edge) b_reg[l] = *(const float4*)(Brow + m0 + c4);
              else {
                float4 bv;
                bv.x = (m0 + c4 + 0 < V_) ? Brow[m0 + c4 + 0] : 0.f;
                bv.y = (m0 + c4 + 1 < V_) ? Brow[m0 + c4 + 1] : 0.f;
                bv.z = (m0 + c4 + 2 < V_) ? Brow[m0 + c4 + 2] : 0.f;
                bv.w = (m0 + c4 + 3 < V_) ? Brow[m0 + c4 + 3] : 0.f;
                b_reg[l] = bv;
              }
            }
          }
#pragma unroll
          for (int kk = 0; kk < 16; kk++) {
            float4 av = *(const float4*)&lAs[kk][tn * 4];
            float4 bv = *(const float4*)&lBs[kk][tm * 4];
            float a[4] = {av.x, av.y, av.z, av.w};
            float b[4] = {bv.x, bv.y, bv.z, bv.w};
#pragma unroll
            for (int i = 0; i < 4; i++)
#pragma unroll
              for (int j = 0; j < 4; j++) acc[i][j] += a[i] * b[j];
          }
        }

        // fused per-tile top-RT / max / expsum
#pragma unroll
        for (int i = 0; i < 4; i++) {
          float vv[RT]; int ii[RT];
#pragma unroll
          for (int q = 0; q < RT; q++) { vv[q] = -3.4e38f; ii[q] = 0x7fffffff; }
          float vals[4];
#pragma unroll
          for (int j = 0; j < 4; j++) {
            const int m = m0 + tm * 4 + j;
            const float v = (m < V_) ? (acc[i][j] + P.bc[m]) : -3.4e38f;
            vals[j] = v;
            if (m < V_) tk_insertN(v, m, vv, ii);
          }
#pragma unroll
          for (int off = 1; off < 32; off <<= 1) {
            float ov[RT]; int oi[RT];
#pragma unroll
            for (int q = 0; q < RT; q++) {
              ov[q] = __shfl_xor(vv[q], off);
              oi[q] = __shfl_xor(ii[q], off);
            }
            tk_merge_reg(vv, ii, ov, oi);
          }
          const float rowmax = vv[0];
          float s = 0.f;
#pragma unroll
          for (int j = 0; j < 4; j++) {
            const int m = m0 + tm * 4 + j;
            if (m < V_) s += expf(vals[j] - rowmax);
          }
#pragma unroll
          for (int off = 1; off < 32; off <<= 1) s += __shfl_xor(s, off);
          const int gr = n0 + tn * 4 + i;
          if (tm == 0 && gr < N) {
            const size_t pb = (size_t)gr * LG_MT + mt;
#pragma unroll
            for (int q = 0; q < RT; q++) {
              P.ptv[pb * RT + q] = vv[q]; P.pti[pb * RT + q] = ii[q];
            }
            P.pmx[pb] = rowmax;
            P.psm[pb] = s;
          }
        }
      }
    }
    gbar(P.bar, &calls);

    // ================= phase E: merge partials + beam select + reorder =====
    for (int b = bid; b < B_; b += nblk) {
      __syncthreads();   // LDS reuse guard
      if (t == 0) {
        merge_row_dev(b, tid, P.ptv, P.pti, P.pmx, P.psm, msv, msi, mred,
                      rmv[0], rmi[0], &rM[0], &rL[0]);
#pragma unroll
        for (int r = 0; r < K_; r++) {
          const int n = b * K_ + r;
          for (int i = tid; i < H_; i += 256) {
            P.h[(size_t)n * H_ + i] = P.h2[(size_t)b * H_ + i];
            P.c[(size_t)n * H_ + i] = P.c2[(size_t)b * H_ + i];
          }
          if (tid < T_) P.pA[tid * N1_ + n] = (tid == 0) ? rmi[0][r] : 0;
          if (tid == 0) {
            const int idx = rmi[0][r];
            P.cumA[n] = (rmv[0][r] - rM[0]) - rL[0];
            P.tok[n] = idx;
            P.eosA[n] = (idx == EOS_) ? 1 : 0;
          }
        }
      } else {
        for (int r = 0; r < K_; r++)
          merge_row_dev(b * K_ + r, tid, P.ptv, P.pti, P.pmx, P.psm,
                        msv, msi, mred, rmv[r], rmi[r], &rM[r], &rL[r]);
        const float* cumOld = (t & 1) ? P.cumA : P.cumB;
        float* cumNew = (t & 1) ? P.cumB : P.cumA;
        const int* eosOld = (t & 1) ? P.eosA : P.eosB;
        int* eosNew = (t & 1) ? P.eosB : P.eosA;
        const int* pOld = (t & 1) ? P.pA : P.pB;
        int* pNew = (t & 1) ? P.pB : P.pA;

        if (tid == 0) {
          float cv[3 * RT]; int cj[3 * RT]; int cnt = 0;
          for (int k = 0; k < K_; k++) {
            const int row = b * K_ + k;
            const float ck = cumOld[row];
            if (eosOld[row]) {
              cv[cnt] = ck; cj[cnt] = k * V_ + EOS_; cnt++;
            } else {
              const float mxk = rM[k], lsk = rL[k];
              for (int q = 0; q < RT; q++) {
                cv[cnt] = ck + ((rmv[k][q] - mxk) - lsk);
                cj[cnt] = k * V_ + rmi[k][q]; cnt++;
              }
            }
          }
          int used = 0;
          for (int rep = 0; rep < K_; rep++) {
            int pick = -1;
            for (int i2 = 0; i2 < cnt; i2++) {
              if ((used >> i2) & 1) continue;
              if (pick < 0 || tk_better(cv[i2], cj[i2], cv[pick], cj[pick])) pick = i2;
            }
            used |= 1 << pick;
            s_val[rep] = cv[pick];
            s_g[rep] = b * K_ + cj[pick] / V_;
            s_tok[rep] = cj[pick] % V_;
          }
        }
        __syncthreads();
#pragma unroll
        for (int r = 0; r < K_; r++) {
          const int n = b * K_ + r;
          const int g = s_g[r], ntok = s_tok[r];
          for (int i = tid; i < H_; i += 256) {
            P.h[(size_t)n * H_ + i] = P.h2[(size_t)g * H_ + i];
            P.c[(size_t)n * H_ + i] = P.c2[(size_t)g * H_ + i];
          }
          if (tid < T_) pNew[tid * N1_ + n] = (tid == t) ? ntok : pOld[tid * N1_ + g];
          if (tid == 0) {
            cumNew[n] = s_val[r];
            eosNew[n] = eosOld[g] | ((ntok == EOS_) ? 1 : 0);
            P.tok[n] = ntok;
          }
        }
      }
    }
    gbar(P.bar, &calls);
  }

  // ================= final output (t=31 odd -> preds in pB, cum in cumB) ===
  for (int i = bid * 256 + tid; i < T_ * B_ + N1_; i += nblk * 256) {
    if (i < T_ * B_) {
      const int tt = i >> 5, b = i & 31;
      P.out[i] = (float)P.pB[tt * N1_ + b * K_];
    } else {
      P.out[i] = P.cumB[i - T_ * B_];
    }
  }
}

// ---------------------------------------------------------------------------
extern "C" void kernel_launch(void* const* d_in, const int* in_sizes, int n_in,
                              void* d_out, int out_size, void* d_ws, size_t ws_size,
                              hipStream_t stream)
{
  const float* enc    = (const float*)d_in[0];
  const float* last_h = (const float*)d_in[1];
  const float* last_c = (const float*)d_in[2];
  const float* mask   = (const float*)d_in[3];
  const float* emb    = (const float*)d_in[5];
  const float* Wp     = (const float*)d_in[6];
  const float* We     = (const float*)d_in[7];
  const float* Wv     = (const float*)d_in[8];
  const float* W_ih   = (const float*)d_in[9];
  const float* W_hh   = (const float*)d_in[10];
  const float* b_ih   = (const float*)d_in[11];
  const float* b_hh   = (const float*)d_in[12];
  const float* Wc     = (const float*)d_in[13];
  const float* bc     = (const float*)d_in[14];
  const float* W_init = (const float*)d_in[15];
  const float* b_init = (const float*)d_in[16];

  // ws carve — ~21.5 MB (< proven 23.69 MB)
  float* w = (float*)d_ws;
  float* encp = w;  w += (size_t)S_ * B_ * H_;   // 16.78 MB
  float* h    = w;  w += N1_ * H_;
  float* c    = w;  w += N1_ * H_;
  float* h2   = w;  w += N1_ * H_;
  float* c2   = w;  w += N1_ * H_;
  float* xcat = w;  w += N1_ * 1280;
  float* gts  = w;  w += 4 * GST;
  float* ptv  = w;  w += (size_t)N1_ * LG_MT * RT;
  float* pmx  = w;  w += (size_t)N1_ * LG_MT;
  float* psm  = w;  w += (size_t)N1_ * LG_MT;
  float* cumA = w;  w += N1_;
  float* cumB = w;  w += N1_;
  int* pti  = (int*)w;  w += (size_t)N1_ * LG_MT * RT;
  int* tok  = (int*)w;  w += N1_;
  int* eosA = (int*)w;  w += N1_;
  int* eosB = (int*)w;  w += N1_;
  int* pA   = (int*)w;  w += T_ * N1_;
  int* pB   = (int*)w;  w += T_ * N1_;
  unsigned* bar = (unsigned*)w; w += 16;

  // grid size: never exceed co-resident capacity (host-only queries,
  // graph-capture safe). Grid-stride phases make any size correct.
  static int g_grid = 0;
  if (g_grid == 0) {
    int nb = 0;
    if (hipOccupancyMaxActiveBlocksPerMultiprocessor(
            &nb, reinterpret_cast<const void*>(decode_k), 256, 0) != hipSuccess ||
        nb < 1)
      nb = 1;
    int dev = 0;
    (void)hipGetDevice(&dev);
    int ncu = 0;
    if (hipDeviceGetAttribute(&ncu, hipDeviceAttributeMultiprocessorCount, dev)
            != hipSuccess || ncu < 1)
      ncu = 256;
    long long cap = (long long)nb * (long long)ncu;
    g_grid = (int)(cap < 256 ? cap : 256);
    if (g_grid < 1) g_grid = 1;
  }

  // barrier counter must start at 0 each replay
  hipMemsetAsync(bar, 0, 64, stream);

  // ---- prologue GEMMs (once) ----
  gemm_k<<<dim3(8, 1, 1), 256, 0, stream>>>(last_h + B_ * H_, W_init, nullptr, H_,
      b_init, nullptr, h, B_, H_, H_, H_, 0);
  gemm_k<<<dim3(8, 1, 1), 256, 0, stream>>>(last_c + B_ * H_, W_init, nullptr, H_,
      b_init, nullptr, c, B_, H_, H_, H_, 0);
  gemm_k<<<dim3(8, 128, 1), 256, 0, stream>>>(enc, We, nullptr, H_,
      nullptr, nullptr, encp, S_ * B_, H_, H_, H_, 0);

  // ---- persistent decode loop ----
  DK P;
  P.enc = enc; P.mask = mask; P.emb = emb; P.Wp = Wp; P.Wv = Wv;
  P.W_ih = W_ih; P.W_hh = W_hh; P.b_ih = b_ih; P.b_hh = b_hh;
  P.Wc = Wc; P.bc = bc; P.encp = encp;
  P.h = h; P.c = c; P.h2 = h2; P.c2 = c2; P.xcat = xcat; P.gts = gts;
  P.ptv = ptv; P.pmx = pmx; P.psm = psm; P.cumA = cumA; P.cumB = cumB;
  P.pti = pti; P.tok = tok; P.eosA = eosA; P.eosB = eosB; P.pA = pA; P.pB = pB;
  P.out = (float*)d_out; P.bar = bar;

  decode_k<<<g_grid, 256, 0, stream>>>(P);
}

// Round 3
// 14168.089 us; speedup vs baseline: 1.0974x; 1.0974x over previous
//
#include <hip/hip_runtime.h>
#include <math.h>

#define S_   256
#define B_   32
#define H_   512
#define E_   256
#define V_   10000
#define K_   3
#define T_   32
#define N1_  96
#define BOS_ 1
#define EOS_ 1
#define NEG_ (-1000000000.0f)
#define RT   4        // per-row top-RT kept for exact beam merge (RT > K suffices)
#define LG_MT 79      // ceil(10000/128) m-tiles in logits GEMM
#define GST  (N1_ * 4 * H_)   // gts part stride (floats)
#define NFLG 256      // barrier flag slots (64B apart)

// ---------------------------------------------------------------------------
// Generic fp32 tiled GEMM — used for the 3 prologue GEMMs only (unchanged).
// ---------------------------------------------------------------------------
__global__ __launch_bounds__(256) void gemm_k(
    const float* __restrict__ A, const float* __restrict__ B1,
    const float* __restrict__ B2, int split,
    const float* __restrict__ bias1, const float* __restrict__ bias2,
    float* __restrict__ C, int N, int Kd, int M, int klen, size_t cstride)
{
  __shared__ float As[16][64];
  __shared__ float Bs[16][64];
  const int tid = threadIdx.x;
  const int m0 = blockIdx.x * 64;
  const int n0 = blockIdx.y * 64;
  const int kstart = blockIdx.z * klen;
  const int kend = kstart + klen;
  const int tm = tid & 15, tn = tid >> 4;
  const int la_n = tid & 63;
  const int la_k = (tid >> 6) * 4;
  const int lb_m = (tid & 15) * 4;
  const int lb_k = tid >> 4;

  const int an = (n0 + la_n < N) ? (n0 + la_n) : 0;   // clamp (store guarded)
  const float* Arow = A + (size_t)an * Kd;
  float* Cpart = C + (size_t)blockIdx.z * cstride;

  float4 a_reg, b_reg;
  a_reg = *(const float4*)(Arow + kstart + la_k);
  {
    int krow = kstart + lb_k;
    const float* Brow = (krow < split) ? (B1 + (size_t)krow * M)
                                       : (B2 + (size_t)(krow - split) * M);
    int m = m0 + lb_m;
    if (m + 3 < M) b_reg = *(const float4*)(Brow + m);
    else {
      b_reg.x = (m + 0 < M) ? Brow[m + 0] : 0.f;
      b_reg.y = (m + 1 < M) ? Brow[m + 1] : 0.f;
      b_reg.z = (m + 2 < M) ? Brow[m + 2] : 0.f;
      b_reg.w = (m + 3 < M) ? Brow[m + 3] : 0.f;
    }
  }

  float acc[4][4] = {};

  for (int k0 = kstart; k0 < kend; k0 += 16) {
    if (k0 > kstart) __syncthreads();
    As[la_k + 0][la_n] = a_reg.x; As[la_k + 1][la_n] = a_reg.y;
    As[la_k + 2][la_n] = a_reg.z; As[la_k + 3][la_n] = a_reg.w;
    *(float4*)&Bs[lb_k][lb_m] = b_reg;
    __syncthreads();
    if (k0 + 16 < kend) {
      a_reg = *(const float4*)(Arow + (k0 + 16) + la_k);
      int krow = k0 + 16 + lb_k;
      const float* Brow = (krow < split) ? (B1 + (size_t)krow * M)
                                         : (B2 + (size_t)(krow - split) * M);
      int m = m0 + lb_m;
      if (m + 3 < M) b_reg = *(const float4*)(Brow + m);
      else {
        b_reg.x = (m + 0 < M) ? Brow[m + 0] : 0.f;
        b_reg.y = (m + 1 < M) ? Brow[m + 1] : 0.f;
        b_reg.z = (m + 2 < M) ? Brow[m + 2] : 0.f;
        b_reg.w = (m + 3 < M) ? Brow[m + 3] : 0.f;
      }
    }
#pragma unroll
    for (int kk = 0; kk < 16; kk++) {
      float4 av = *(const float4*)&As[kk][tn * 4];
      float4 bv = *(const float4*)&Bs[kk][tm * 4];
      float a[4] = {av.x, av.y, av.z, av.w};
      float b[4] = {bv.x, bv.y, bv.z, bv.w};
#pragma unroll
      for (int i = 0; i < 4; i++)
#pragma unroll
        for (int j = 0; j < 4; j++) acc[i][j] += a[i] * b[j];
    }
  }

  const bool addBias = (blockIdx.z == 0);
#pragma unroll
  for (int i = 0; i < 4; i++) {
    int n = n0 + tn * 4 + i;
    if (n >= N) continue;
#pragma unroll
    for (int j = 0; j < 4; j++) {
      int m = m0 + tm * 4 + j;
      if (m >= M) continue;
      float v = acc[i][j];
      if (addBias && bias1) v += bias1[m];
      if (addBias && bias2) v += bias2[m];
      Cpart[(size_t)n * M + m] = v;
    }
  }
}

// ---- top-k helpers (jax tie-break: value desc, then smaller index) ----
__device__ __forceinline__ bool tk_better(float va, int ia, float vb, int ib) {
  return (va > vb) || (va == vb && ia < ib);
}
__device__ __forceinline__ void tk_insertN(float v, int i, float* vv, int* ii) {
  if (!tk_better(v, i, vv[RT - 1], ii[RT - 1])) return;
  vv[RT - 1] = v; ii[RT - 1] = i;
#pragma unroll
  for (int q = RT - 1; q > 0; q--) {
    if (tk_better(vv[q], ii[q], vv[q - 1], ii[q - 1])) {
      float tv = vv[q]; vv[q] = vv[q - 1]; vv[q - 1] = tv;
      int ti = ii[q]; ii[q] = ii[q - 1]; ii[q - 1] = ti;
    }
  }
}
// merge sorted list (bv2,bi2) into (av,ai), keep RT best
__device__ __forceinline__ void tk_merge_reg(float* av, int* ai,
                                             const float* bv2, const int* bi2) {
  float rv[RT]; int ri[RT];
  int p = 0, q = 0;
#pragma unroll
  for (int t = 0; t < RT; t++) {
    bool ta;
    if (p >= RT) ta = false;
    else if (q >= RT) ta = true;
    else ta = tk_better(av[p], ai[p], bv2[q], bi2[q]);
    if (ta) { rv[t] = av[p]; ri[t] = ai[p]; p++; }
    else    { rv[t] = bv2[q]; ri[t] = bi2[q]; q++; }
  }
#pragma unroll
  for (int t = 0; t < RT; t++) { av[t] = rv[t]; ai[t] = ri[t]; }
}
// LDS pairwise merge
__device__ __forceinline__ void tk_merge_lds(float* sv, int* si, int a, int b) {
  float rv[RT]; int ri[RT];
  int p = 0, q = 0;
#pragma unroll
  for (int t = 0; t < RT; t++) {
    bool ta;
    if (p >= RT) ta = false;
    else if (q >= RT) ta = true;
    else ta = tk_better(sv[a + p], si[a + p], sv[b + q], si[b + q]);
    if (ta) { rv[t] = sv[a + p]; ri[t] = si[a + p]; p++; }
    else    { rv[t] = sv[b + q]; ri[t] = si[b + q]; q++; }
  }
#pragma unroll
  for (int t = 0; t < RT; t++) { sv[a + t] = rv[t]; si[a + t] = ri[t]; }
}

__device__ __forceinline__ float sigf(float x) { return 1.f / (1.f + expf(-x)); }

// ---------------------------------------------------------------------------
// merge of LG_MT per-tile partials for one row -> top-RT + max + lse (in LDS).
// ---------------------------------------------------------------------------
__device__ void merge_row_dev(int n, int tid,
    const float* __restrict__ ptv, const int* __restrict__ pti,
    const float* __restrict__ pmx, const float* __restrict__ psm,
    float* msv, int* msi, float* mred,
    float* outv, int* outi, float* outM, float* outL)
{
  float mx_t = -3.4e38f, sm_t = 0.f;
  if (tid < 128) {
    float vv[RT]; int ii[RT];
#pragma unroll
    for (int q = 0; q < RT; q++) { vv[q] = -3.4e38f; ii[q] = 0x7fffffff; }
    if (tid < LG_MT) {
      const size_t pb = (size_t)n * LG_MT + tid;
#pragma unroll
      for (int q = 0; q < RT; q++) { vv[q] = ptv[pb * RT + q]; ii[q] = pti[pb * RT + q]; }
      mx_t = pmx[pb]; sm_t = psm[pb];
    }
#pragma unroll
    for (int q = 0; q < RT; q++) { msv[tid * RT + q] = vv[q]; msi[tid * RT + q] = ii[q]; }
  }
  __syncthreads();
  for (int st = 64; st; st >>= 1) {
    if (tid < st) tk_merge_lds(msv, msi, tid * RT, (tid + st) * RT);
    __syncthreads();
  }
  if (tid < 128) mred[tid] = mx_t;
  __syncthreads();
  for (int st = 64; st; st >>= 1) {
    if (tid < st) mred[tid] = fmaxf(mred[tid], mred[tid + st]);
    __syncthreads();
  }
  const float Mg = mred[0];
  __syncthreads();
  if (tid < 128) mred[tid] = sm_t * expf(mx_t - Mg);
  __syncthreads();
  for (int st = 64; st; st >>= 1) {
    if (tid < st) mred[tid] += mred[tid + st];
    __syncthreads();
  }
  if (tid == 0) {
    *outM = Mg; *outL = logf(mred[0]);
#pragma unroll
    for (int q = 0; q < RT; q++) { outv[q] = msv[q]; outi[q] = msi[q]; }
  }
  __syncthreads();
}

// ---------------------------------------------------------------------------
// Persistent decode kernel params
// ---------------------------------------------------------------------------
struct DK {
  const float *enc, *mask, *emb, *Wp, *Wv, *W_ih, *W_hh, *b_ih, *b_hh, *Wc, *bc;
  const float *encp;
  float *h, *c, *h2, *c2, *xcat, *gts;
  float *ptv, *pmx, *psm, *cumA, *cumB;
  int *pti, *tok, *eosA, *eosB, *pA, *pB;
  float *out;
  unsigned *flags;   // NFLG slots, 16 u32 (64B) apart
  unsigned *go;      // release line
};

// ---------------------------------------------------------------------------
// Gather-release device barrier: NO atomic RMW. Each block release-stores an
// epoch to its own 64B flag line; block 0 polls all flags (relaxed, parallel
// across its threads), fences, then release-stores the epoch to `go`;
// followers poll `go` relaxed then fence. Timeout escape (~20ms) turns any
// residency failure into a wrong answer instead of a GPU hang.
// ---------------------------------------------------------------------------
__device__ __forceinline__ void gbar(const DK& P, unsigned* pep) {
  __syncthreads();
  const unsigned ep = ++(*pep);
  const int nb = (int)gridDim.x;
  if (blockIdx.x == 0) {
    for (int i = threadIdx.x; i < nb; i += blockDim.x) {
      if (i == 0) continue;
      const long long t0 = (long long)__builtin_amdgcn_s_memrealtime();
      while (__hip_atomic_load(&P.flags[i * 16], __ATOMIC_RELAXED,
                               __HIP_MEMORY_SCOPE_AGENT) < ep) {
        __builtin_amdgcn_s_sleep(2);
        if ((long long)__builtin_amdgcn_s_memrealtime() - t0 > 2000000LL) break;
      }
    }
    __syncthreads();
    if (threadIdx.x == 0) {
      __threadfence();   // wb+inv: publish phase writes, see followers' writes
      __hip_atomic_store(P.go, ep, __ATOMIC_RELEASE, __HIP_MEMORY_SCOPE_AGENT);
    }
  } else {
    if (threadIdx.x == 0) {
      __hip_atomic_store(&P.flags[blockIdx.x * 16], ep, __ATOMIC_RELEASE,
                         __HIP_MEMORY_SCOPE_AGENT);
      const long long t0 = (long long)__builtin_amdgcn_s_memrealtime();
      while (__hip_atomic_load(P.go, __ATOMIC_RELAXED,
                               __HIP_MEMORY_SCOPE_AGENT) < ep) {
        __builtin_amdgcn_s_sleep(2);
        if ((long long)__builtin_amdgcn_s_memrealtime() - t0 > 2000000LL) break;
      }
      __threadfence();   // acquire: invalidate caches to see all phase writes
    }
  }
  __syncthreads();
}

// ---------------------------------------------------------------------------
// Logits GEMM tile body (verbatim from verified version), as a helper so the
// XCD-grouped job mapping can call it.
// ---------------------------------------------------------------------------
__device__ __forceinline__ void lgtile_dev(const DK& P, int N, int mt, int nb2,
    int tid, float (*lAs)[32], float (*lBs)[128])
{
  const int m0 = mt * 128;
  const int n0 = nb2 * 32;
  const int tm = tid & 31;
  const int tn = tid >> 5;
  const bool aload = tid < 128;
  const int ar = tid & 31;
  const int ak = ((tid >> 5) & 3) * 4;
  const int arow_idx = (n0 + ar < N) ? (n0 + ar) : 0;
  const float* Arow = P.xcat + (size_t)arow_idx * 1280;
  const bool edge = (m0 + 128 > V_);

  float4 a_reg = make_float4(0.f, 0.f, 0.f, 0.f);
  float4 b_reg[2];
  if (aload) a_reg = *(const float4*)(Arow + ak);
#pragma unroll
  for (int l = 0; l < 2; l++) {
    const int idx = l * 256 + tid;
    const int kr = idx >> 5, c4 = (idx & 31) * 4;
    const float* Brow = P.Wc + (size_t)kr * V_;
    if (!edge) b_reg[l] = *(const float4*)(Brow + m0 + c4);
    else {
      float4 bv;
      bv.x = (m0 + c4 + 0 < V_) ? Brow[m0 + c4 + 0] : 0.f;
      bv.y = (m0 + c4 + 1 < V_) ? Brow[m0 + c4 + 1] : 0.f;
      bv.z = (m0 + c4 + 2 < V_) ? Brow[m0 + c4 + 2] : 0.f;
      bv.w = (m0 + c4 + 3 < V_) ? Brow[m0 + c4 + 3] : 0.f;
      b_reg[l] = bv;
    }
  }

  float acc[4][4] = {};
  for (int k0 = 0; k0 < 1280; k0 += 16) {
    if (k0 > 0) __syncthreads();
    if (aload) {
      lAs[ak + 0][ar] = a_reg.x; lAs[ak + 1][ar] = a_reg.y;
      lAs[ak + 2][ar] = a_reg.z; lAs[ak + 3][ar] = a_reg.w;
    }
#pragma unroll
    for (int l = 0; l < 2; l++) {
      const int idx = l * 256 + tid;
      const int kr = idx >> 5, c4 = (idx & 31) * 4;
      *(float4*)&lBs[kr][c4] = b_reg[l];
    }
    __syncthreads();
    if (k0 + 16 < 1280) {
      if (aload) a_reg = *(const float4*)(Arow + (k0 + 16) + ak);
#pragma unroll
      for (int l = 0; l < 2; l++) {
        const int idx = l * 256 + tid;
        const int kr = k0 + 16 + (idx >> 5), c4 = (idx & 31) * 4;
        const float* Brow = P.Wc + (size_t)kr * V_;
        if (!edge) b_reg[l] = *(const float4*)(Brow + m0 + c4);
        else {
          float4 bv;
          bv.x = (m0 + c4 + 0 < V_) ? Brow[m0 + c4 + 0] : 0.f;
          bv.y = (m0 + c4 + 1 < V_) ? Brow[m0 + c4 + 1] : 0.f;
          bv.z = (m0 + c4 + 2 < V_) ? Brow[m0 + c4 + 2] : 0.f;
          bv.w = (m0 + c4 + 3 < V_) ? Brow[m0 + c4 + 3] : 0.f;
          b_reg[l] = bv;
        }
      }
    }
#pragma unroll
    for (int kk = 0; kk < 16; kk++) {
      float4 av = *(const float4*)&lAs[kk][tn * 4];
      float4 bv = *(const float4*)&lBs[kk][tm * 4];
      float a[4] = {av.x, av.y, av.z, av.w};
      float b[4] = {bv.x, bv.y, bv.z, bv.w};
#pragma unroll
      for (int i = 0; i < 4; i++)
#pragma unroll
        for (int j = 0; j < 4; j++) acc[i][j] += a[i] * b[j];
    }
  }

  // fused per-tile top-RT / max / expsum
#pragma unroll
  for (int i = 0; i < 4; i++) {
    float vv[RT]; int ii[RT];
#pragma unroll
    for (int q = 0; q < RT; q++) { vv[q] = -3.4e38f; ii[q] = 0x7fffffff; }
    float vals[4];
#pragma unroll
    for (int j = 0; j < 4; j++) {
      const int m = m0 + tm * 4 + j;
      const float v = (m < V_) ? (acc[i][j] + P.bc[m]) : -3.4e38f;
      vals[j] = v;
      if (m < V_) tk_insertN(v, m, vv, ii);
    }
#pragma unroll
    for (int off = 1; off < 32; off <<= 1) {
      float ov[RT]; int oi[RT];
#pragma unroll
      for (int q = 0; q < RT; q++) {
        ov[q] = __shfl_xor(vv[q], off);
        oi[q] = __shfl_xor(ii[q], off);
      }
      tk_merge_reg(vv, ii, ov, oi);
    }
    const float rowmax = vv[0];
    float s = 0.f;
#pragma unroll
    for (int j = 0; j < 4; j++) {
      const int m = m0 + tm * 4 + j;
      if (m < V_) s += expf(vals[j] - rowmax);
    }
#pragma unroll
    for (int off = 1; off < 32; off <<= 1) s += __shfl_xor(s, off);
    const int gr = n0 + tn * 4 + i;
    if (tm == 0 && gr < N) {
      const size_t pb = (size_t)gr * LG_MT + mt;
#pragma unroll
      for (int q = 0; q < RT; q++) {
        P.ptv[pb * RT + q] = vv[q]; P.pti[pb * RT + q] = ii[q];
      }
      P.pmx[pb] = rowmax;
      P.psm[pb] = s;
    }
  }
}

// ---------------------------------------------------------------------------
// One persistent kernel for the whole T=32 decode loop. Grid from occupancy
// API; every phase grid-strides its job count so any grid size is correct.
// ---------------------------------------------------------------------------
__global__ __launch_bounds__(256) void decode_k(DK P)
{
  const int bid = blockIdx.x;
  const int nblk = gridDim.x;
  const int tid = threadIdx.x;
  unsigned ep = 0;

  __shared__ float gAs[16][64];   // gates GEMM
  __shared__ float gBs[16][64];
  __shared__ float lAs[16][32];   // logits GEMM
  __shared__ float lBs[16][128];
  __shared__ float hS[512];       // attention phase
  __shared__ float ppS[512];
  __shared__ float WvS[512];
  __shared__ float scS[256];
  __shared__ float red[256];
  __shared__ float msv[128 * RT]; // merge phase
  __shared__ int   msi[128 * RT];
  __shared__ float mred[128];
  __shared__ float rmv[K_][RT];
  __shared__ int   rmi[K_][RT];
  __shared__ float rM[K_], rL[K_];
  __shared__ float s_val[K_];
  __shared__ int   s_g[K_], s_tok[K_];

  for (int t = 0; t < T_; t++) {
    const int N = (t == 0) ? B_ : N1_;

    // ================= phase A: attention (pp + scores + softmax + ctx) ====
    for (int n = bid; n < N; n += nblk) {
      __syncthreads();   // LDS reuse guard between job iterations
      const int b = (t == 0) ? n : (n / K_);
      float* xr = P.xcat + (size_t)n * 1280;

      const float hv0 = P.h[(size_t)n * H_ + tid];
      const float hv1 = P.h[(size_t)n * H_ + 256 + tid];
      hS[tid] = hv0; hS[256 + tid] = hv1;
      WvS[tid] = P.Wv[tid]; WvS[256 + tid] = P.Wv[256 + tid];
      xr[E_ + H_ + tid] = hv0;                 // hprev
      xr[E_ + H_ + 256 + tid] = hv1;
      {
        const int tk = (t == 0) ? BOS_ : P.tok[n];
        xr[tid] = P.emb[(size_t)tk * E_ + tid];  // ex (tid spans 0..255 == E_)
      }
      __syncthreads();

      // pp = h @ Wp — 4 k-chunks of 128, combined left-assoc
      {
        float p00 = 0.f, p01 = 0.f, p02 = 0.f, p03 = 0.f;
        float p10 = 0.f, p11 = 0.f, p12 = 0.f, p13 = 0.f;
#pragma unroll 4
        for (int kk = 0; kk < 128; kk++) {
          const float h0 = hS[kk], h1 = hS[128 + kk];
          const float h2v = hS[256 + kk], h3 = hS[384 + kk];
          const float* wr0 = P.Wp + (size_t)kk * H_;
          const float* wr1 = P.Wp + (size_t)(128 + kk) * H_;
          const float* wr2 = P.Wp + (size_t)(256 + kk) * H_;
          const float* wr3 = P.Wp + (size_t)(384 + kk) * H_;
          p00 += h0 * wr0[tid];        p01 += h1 * wr1[tid];
          p02 += h2v * wr2[tid];       p03 += h3 * wr3[tid];
          p10 += h0 * wr0[256 + tid];  p11 += h1 * wr1[256 + tid];
          p12 += h2v * wr2[256 + tid]; p13 += h3 * wr3[256 + tid];
        }
        ppS[tid] = p00 + p01 + p02 + p03;
        ppS[256 + tid] = p10 + p11 + p12 + p13;
      }
      __syncthreads();

      // scores (one warp per s mod 4)
      {
        const int w = tid >> 6, lane = tid & 63;
        for (int s = w; s < S_; s += 4) {
          const float* ep2 = P.encp + ((size_t)s * B_ + b) * H_;
          float acc = 0.f;
#pragma unroll
          for (int r = 0; r < 8; r++) {
            const int hh = r * 64 + lane;
            acc += tanhf(ppS[hh] + ep2[hh]) * WvS[hh];
          }
#pragma unroll
          for (int off = 32; off; off >>= 1) acc += __shfl_xor(acc, off);
          if (lane == 0)
            scS[s] = (P.mask[(size_t)b * S_ + s] == 0.f) ? NEG_ : acc;
        }
      }
      __syncthreads();

      // softmax (same pairwise trees as verified ctx_k)
      float v = scS[tid];
      red[tid] = v; __syncthreads();
      for (int st = 128; st; st >>= 1) {
        if (tid < st) red[tid] = fmaxf(red[tid], red[tid + st]);
        __syncthreads();
      }
      const float mx = red[0]; __syncthreads();
      const float e = expf(v - mx);
      scS[tid] = e;
      red[tid] = e; __syncthreads();
      for (int st = 128; st; st >>= 1) {
        if (tid < st) red[tid] += red[tid + st];
        __syncthreads();
      }
      const float rsum = 1.f / red[0];
      __syncthreads();

      // ctx — 4 s-phase partials per col, combined left-assoc
      {
        float c00 = 0.f, c01 = 0.f, c02 = 0.f, c03 = 0.f;
        float c10 = 0.f, c11 = 0.f, c12 = 0.f, c13 = 0.f;
#pragma unroll 2
        for (int s0 = 0; s0 < S_; s0 += 4) {
          const float a0 = scS[s0 + 0], a1 = scS[s0 + 1];
          const float a2 = scS[s0 + 2], a3 = scS[s0 + 3];
          const float* e0 = P.enc + ((size_t)(s0 + 0) * B_ + b) * H_;
          const float* e1 = P.enc + ((size_t)(s0 + 1) * B_ + b) * H_;
          const float* e2 = P.enc + ((size_t)(s0 + 2) * B_ + b) * H_;
          const float* e3 = P.enc + ((size_t)(s0 + 3) * B_ + b) * H_;
          c00 += a0 * e0[tid];       c01 += a1 * e1[tid];
          c02 += a2 * e2[tid];       c03 += a3 * e3[tid];
          c10 += a0 * e0[256 + tid]; c11 += a1 * e1[256 + tid];
          c12 += a2 * e2[256 + tid]; c13 += a3 * e3[256 + tid];
        }
        xr[E_ + tid] = (c00 + c01 + c02 + c03) * rsum;
        xr[E_ + 256 + tid] = (c10 + c11 + c12 + c13) * rsum;
      }
    }
    gbar(P, &ep);

    // ================= phase B: gates GEMM (64x64 tiles, split-K 4) ========
    {
      const int ntiles = (t == 0) ? 1 : 2;
      const int jobs = 32 * ntiles * 4;
      for (int job = bid; job < jobs; job += nblk) {
        __syncthreads();   // LDS reuse guard
        const int bx = job & 31;
        const int rem = job >> 5;
        const int by = rem % ntiles;
        const int bz = rem / ntiles;
        const int m0 = bx * 64;
        const int n0 = by * 64;
        const int kstart = bz * 320;
        const int kend = kstart + 320;
        const int tm = tid & 15, tn = tid >> 4;
        const int la_n = tid & 63;
        const int la_k = (tid >> 6) * 4;
        const int lb_m = (tid & 15) * 4;
        const int lb_k = tid >> 4;
        const int an = (n0 + la_n < N) ? (n0 + la_n) : 0;
        const float* Arow = P.xcat + (size_t)an * 1280;
        float* Cpart = P.gts + (size_t)bz * GST;

        float4 a_reg = *(const float4*)(Arow + kstart + la_k);
        float4 b_reg;
        {
          const int krow = kstart + lb_k;
          const float* Brow = (krow < 768) ? (P.W_ih + (size_t)krow * 2048)
                                           : (P.W_hh + (size_t)(krow - 768) * 2048);
          b_reg = *(const float4*)(Brow + m0 + lb_m);   // M=2048, no edge
        }
        float acc[4][4] = {};
        for (int k0 = kstart; k0 < kend; k0 += 16) {
          if (k0 > kstart) __syncthreads();
          gAs[la_k + 0][la_n] = a_reg.x; gAs[la_k + 1][la_n] = a_reg.y;
          gAs[la_k + 2][la_n] = a_reg.z; gAs[la_k + 3][la_n] = a_reg.w;
          *(float4*)&gBs[lb_k][lb_m] = b_reg;
          __syncthreads();
          if (k0 + 16 < kend) {
            a_reg = *(const float4*)(Arow + (k0 + 16) + la_k);
            const int krow = k0 + 16 + lb_k;
            const float* Brow = (krow < 768) ? (P.W_ih + (size_t)krow * 2048)
                                             : (P.W_hh + (size_t)(krow - 768) * 2048);
            b_reg = *(const float4*)(Brow + m0 + lb_m);
          }
#pragma unroll
          for (int kk = 0; kk < 16; kk++) {
            float4 av = *(const float4*)&gAs[kk][tn * 4];
            float4 bv = *(const float4*)&gBs[kk][tm * 4];
            float a[4] = {av.x, av.y, av.z, av.w};
            float b[4] = {bv.x, bv.y, bv.z, bv.w};
#pragma unroll
            for (int i = 0; i < 4; i++)
#pragma unroll
              for (int j = 0; j < 4; j++) acc[i][j] += a[i] * b[j];
          }
        }
        const bool addBias = (bz == 0);
#pragma unroll
        for (int i = 0; i < 4; i++) {
          const int n = n0 + tn * 4 + i;
          if (n >= N) continue;
#pragma unroll
          for (int j = 0; j < 4; j++) {
            const int m = m0 + tm * 4 + j;
            float vv = acc[i][j];
            if (addBias) { vv += P.b_ih[m]; vv += P.b_hh[m]; }
            Cpart[(size_t)n * 2048 + m] = vv;
          }
        }
      }
    }
    gbar(P, &ep);

    // ================= phase C: LSTM pointwise =============================
    for (int n = bid; n < N; n += nblk) {
      float* xr = P.xcat + (size_t)n * 1280;
      for (int i = tid; i < H_; i += 256) {
        float gi = 0.f, gf = 0.f, gg = 0.f, go = 0.f;
#pragma unroll
        for (int p = 0; p < 4; p++) {
          const float* g = P.gts + (size_t)p * GST + (size_t)n * (4 * H_);
          gi += g[i]; gf += g[H_ + i]; gg += g[2 * H_ + i]; go += g[3 * H_ + i];
        }
        const float ctx_i = xr[E_ + i];
        const float cc = P.c[(size_t)n * H_ + i];
        const float cv = sigf(gf) * cc + sigf(gi) * tanhf(gg);
        const float hv = sigf(go) * tanhf(cv);
        P.c2[(size_t)n * H_ + i] = cv;
        P.h2[(size_t)n * H_ + i] = hv;
        xr[E_ + i] = hv;
        xr[E_ + H_ + i] = ctx_i;
      }
    }
    gbar(P, &ep);

    // ================= phase D: logits GEMM + fused top-RT epilogue ========
    // XCD-grouped job mapping (t>0): the 3 n-tiles of one Wc m-tile land on
    // blocks with equal bid%8 (same XCD under round-robin dispatch) so the
    // 655KB Wc tile is read once into that XCD's L2 and hit twice.
    {
      if (t == 0) {
        for (int job = bid; job < LG_MT; job += nblk) {
          __syncthreads();   // LDS reuse guard
          lgtile_dev(P, N, job, 0, tid, lAs, lBs);
        }
      } else {
        for (int v = bid; v < 240; v += nblk) {
          const int x = v & 7, l = v >> 3;
          if (l >= 30) continue;               // uniform per block
          const int mt = x * 10 + l / 3;
          if (mt >= LG_MT) continue;           // uniform per block
          __syncthreads();   // LDS reuse guard
          lgtile_dev(P, N, mt, l % 3, tid, lAs, lBs);
        }
      }
    }
    gbar(P, &ep);

    // ================= phase E: merge partials + beam select + reorder =====
    for (int b = bid; b < B_; b += nblk) {
      __syncthreads();   // LDS reuse guard
      if (t == 0) {
        merge_row_dev(b, tid, P.ptv, P.pti, P.pmx, P.psm, msv, msi, mred,
                      rmv[0], rmi[0], &rM[0], &rL[0]);
#pragma unroll
        for (int r = 0; r < K_; r++) {
          const int n = b * K_ + r;
          for (int i = tid; i < H_; i += 256) {
            P.h[(size_t)n * H_ + i] = P.h2[(size_t)b * H_ + i];
            P.c[(size_t)n * H_ + i] = P.c2[(size_t)b * H_ + i];
          }
          if (tid < T_) P.pA[tid * N1_ + n] = (tid == 0) ? rmi[0][r] : 0;
          if (tid == 0) {
            const int idx = rmi[0][r];
            P.cumA[n] = (rmv[0][r] - rM[0]) - rL[0];
            P.tok[n] = idx;
            P.eosA[n] = (idx == EOS_) ? 1 : 0;
          }
        }
      } else {
        for (int r = 0; r < K_; r++)
          merge_row_dev(b * K_ + r, tid, P.ptv, P.pti, P.pmx, P.psm,
                        msv, msi, mred, rmv[r], rmi[r], &rM[r], &rL[r]);
        const float* cumOld = (t & 1) ? P.cumA : P.cumB;
        float* cumNew = (t & 1) ? P.cumB : P.cumA;
        const int* eosOld = (t & 1) ? P.eosA : P.eosB;
        int* eosNew = (t & 1) ? P.eosB : P.eosA;
        const int* pOld = (t & 1) ? P.pA : P.pB;
        int* pNew = (t & 1) ? P.pB : P.pA;

        if (tid == 0) {
          float cv[3 * RT]; int cj[3 * RT]; int cnt = 0;
          for (int k = 0; k < K_; k++) {
            const int row = b * K_ + k;
            const float ck = cumOld[row];
            if (eosOld[row]) {
              cv[cnt] = ck; cj[cnt] = k * V_ + EOS_; cnt++;
            } else {
              const float mxk = rM[k], lsk = rL[k];
              for (int q = 0; q < RT; q++) {
                cv[cnt] = ck + ((rmv[k][q] - mxk) - lsk);
                cj[cnt] = k * V_ + rmi[k][q]; cnt++;
              }
            }
          }
          int used = 0;
          for (int rep = 0; rep < K_; rep++) {
            int pick = -1;
            for (int i2 = 0; i2 < cnt; i2++) {
              if ((used >> i2) & 1) continue;
              if (pick < 0 || tk_better(cv[i2], cj[i2], cv[pick], cj[pick])) pick = i2;
            }
            used |= 1 << pick;
            s_val[rep] = cv[pick];
            s_g[rep] = b * K_ + cj[pick] / V_;
            s_tok[rep] = cj[pick] % V_;
          }
        }
        __syncthreads();
#pragma unroll
        for (int r = 0; r < K_; r++) {
          const int n = b * K_ + r;
          const int g = s_g[r], ntok = s_tok[r];
          for (int i = tid; i < H_; i += 256) {
            P.h[(size_t)n * H_ + i] = P.h2[(size_t)g * H_ + i];
            P.c[(size_t)n * H_ + i] = P.c2[(size_t)g * H_ + i];
          }
          if (tid < T_) pNew[tid * N1_ + n] = (tid == t) ? ntok : pOld[tid * N1_ + g];
          if (tid == 0) {
            cumNew[n] = s_val[r];
            eosNew[n] = eosOld[g] | ((ntok == EOS_) ? 1 : 0);
            P.tok[n] = ntok;
          }
        }
      }
    }
    gbar(P, &ep);
  }

  // ================= final output (t=31 odd -> preds in pB, cum in cumB) ===
  for (int i = bid * 256 + tid; i < T_ * B_ + N1_; i += nblk * 256) {
    if (i < T_ * B_) {
      const int tt = i >> 5, b = i & 31;
      P.out[i] = (float)P.pB[tt * N1_ + b * K_];
    } else {
      P.out[i] = P.cumB[i - T_ * B_];
    }
  }
}

// ---------------------------------------------------------------------------
extern "C" void kernel_launch(void* const* d_in, const int* in_sizes, int n_in,
                              void* d_out, int out_size, void* d_ws, size_t ws_size,
                              hipStream_t stream)
{
  const float* enc    = (const float*)d_in[0];
  const float* last_h = (const float*)d_in[1];
  const float* last_c = (const float*)d_in[2];
  const float* mask   = (const float*)d_in[3];
  const float* emb    = (const float*)d_in[5];
  const float* Wp     = (const float*)d_in[6];
  const float* We     = (const float*)d_in[7];
  const float* Wv     = (const float*)d_in[8];
  const float* W_ih   = (const float*)d_in[9];
  const float* W_hh   = (const float*)d_in[10];
  const float* b_ih   = (const float*)d_in[11];
  const float* b_hh   = (const float*)d_in[12];
  const float* Wc     = (const float*)d_in[13];
  const float* bc     = (const float*)d_in[14];
  const float* W_init = (const float*)d_in[15];
  const float* b_init = (const float*)d_in[16];

  // ws carve — ~21.6 MB (< proven 23.69 MB)
  float* w = (float*)d_ws;
  float* encp = w;  w += (size_t)S_ * B_ * H_;   // 16.78 MB
  float* h    = w;  w += N1_ * H_;
  float* c    = w;  w += N1_ * H_;
  float* h2   = w;  w += N1_ * H_;
  float* c2   = w;  w += N1_ * H_;
  float* xcat = w;  w += N1_ * 1280;
  float* gts  = w;  w += 4 * GST;
  float* ptv  = w;  w += (size_t)N1_ * LG_MT * RT;
  float* pmx  = w;  w += (size_t)N1_ * LG_MT;
  float* psm  = w;  w += (size_t)N1_ * LG_MT;
  float* cumA = w;  w += N1_;
  float* cumB = w;  w += N1_;
  int* pti  = (int*)w;  w += (size_t)N1_ * LG_MT * RT;
  int* tok  = (int*)w;  w += N1_;
  int* eosA = (int*)w;  w += N1_;
  int* eosB = (int*)w;  w += N1_;
  int* pA   = (int*)w;  w += T_ * N1_;
  int* pB   = (int*)w;  w += T_ * N1_;
  unsigned* flags = (unsigned*)w;  w += NFLG * 16 + 16;   // + go line

  // grid size: never exceed co-resident capacity (host-only queries,
  // graph-capture safe). Grid-stride phases make any size correct.
  static int g_grid = 0;
  if (g_grid == 0) {
    int nb = 0;
    if (hipOccupancyMaxActiveBlocksPerMultiprocessor(
            &nb, reinterpret_cast<const void*>(decode_k), 256, 0) != hipSuccess ||
        nb < 1)
      nb = 1;
    int dev = 0;
    (void)hipGetDevice(&dev);
    int ncu = 0;
    if (hipDeviceGetAttribute(&ncu, hipDeviceAttributeMultiprocessorCount, dev)
            != hipSuccess || ncu < 1)
      ncu = 256;
    long long cap = (long long)nb * (long long)ncu;
    g_grid = (int)(cap < NFLG ? cap : NFLG);
    if (g_grid < 1) g_grid = 1;
  }

  // barrier flags + go must start at 0 each replay
  hipMemsetAsync(flags, 0, (NFLG * 16 + 16) * sizeof(unsigned), stream);

  // ---- prologue GEMMs (once) ----
  gemm_k<<<dim3(8, 1, 1), 256, 0, stream>>>(last_h + B_ * H_, W_init, nullptr, H_,
      b_init, nullptr, h, B_, H_, H_, H_, 0);
  gemm_k<<<dim3(8, 1, 1), 256, 0, stream>>>(last_c + B_ * H_, W_init, nullptr, H_,
      b_init, nullptr, c, B_, H_, H_, H_, 0);
  gemm_k<<<dim3(8, 128, 1), 256, 0, stream>>>(enc, We, nullptr, H_,
      nullptr, nullptr, encp, S_ * B_, H_, H_, H_, 0);

  // ---- persistent decode loop ----
  DK P;
  P.enc = enc; P.mask = mask; P.emb = emb; P.Wp = Wp; P.Wv = Wv;
  P.W_ih = W_ih; P.W_hh = W_hh; P.b_ih = b_ih; P.b_hh = b_hh;
  P.Wc = Wc; P.bc = bc; P.encp = encp;
  P.h = h; P.c = c; P.h2 = h2; P.c2 = c2; P.xcat = xcat; P.gts = gts;
  P.ptv = ptv; P.pmx = pmx; P.psm = psm; P.cumA = cumA; P.cumB = cumB;
  P.pti = pti; P.tok = tok; P.eosA = eosA; P.eosB = eosB; P.pA = pA; P.pB = pB;
  P.out = (float*)d_out;
  P.flags = flags; P.go = flags + NFLG * 16;

  decode_k<<<g_grid, 256, 0, stream>>>(P);
}

// Round 4
// 10243.774 us; speedup vs baseline: 1.5177x; 1.3831x over previous
//
#include <hip/hip_runtime.h>
#include <math.h>

#define S_   256
#define B_   32
#define H_   512
#define E_   256
#define V_   10000
#define K_   3
#define T_   32
#define N1_  96
#define BOS_ 1
#define EOS_ 1
#define NEG_ (-1000000000.0f)
#define RT   4        // per-row top-RT kept for exact beam merge (RT > K suffices)
#define LG_MT 79      // ceil(10000/128) m-tiles in logits GEMM
#define GST  (N1_ * 4 * H_)   // gts part stride (floats)

// ---------------------------------------------------------------------------
// Generic fp32 tiled GEMM (prologue + gts): 64x64 tile, TK=16, 256 thr, 4x4
// thread tile, register-prefetch double buffering, split-K via blockIdx.z.
// (verbatim from the 6882us-verified kernel)
// ---------------------------------------------------------------------------
__global__ __launch_bounds__(256) void gemm_k(
    const float* __restrict__ A, const float* __restrict__ B1,
    const float* __restrict__ B2, int split,
    const float* __restrict__ bias1, const float* __restrict__ bias2,
    float* __restrict__ C, int N, int Kd, int M, int klen, size_t cstride)
{
  __shared__ float As[16][64];
  __shared__ float Bs[16][64];
  const int tid = threadIdx.x;
  const int m0 = blockIdx.x * 64;
  const int n0 = blockIdx.y * 64;
  const int kstart = blockIdx.z * klen;
  const int kend = kstart + klen;
  const int tm = tid & 15, tn = tid >> 4;
  const int la_n = tid & 63;
  const int la_k = (tid >> 6) * 4;
  const int lb_m = (tid & 15) * 4;
  const int lb_k = tid >> 4;

  const int an = (n0 + la_n < N) ? (n0 + la_n) : 0;   // clamp (store guarded)
  const float* Arow = A + (size_t)an * Kd;
  float* Cpart = C + (size_t)blockIdx.z * cstride;

  float4 a_reg, b_reg;
  a_reg = *(const float4*)(Arow + kstart + la_k);
  {
    int krow = kstart + lb_k;
    const float* Brow = (krow < split) ? (B1 + (size_t)krow * M)
                                       : (B2 + (size_t)(krow - split) * M);
    int m = m0 + lb_m;
    if (m + 3 < M) b_reg = *(const float4*)(Brow + m);
    else {
      b_reg.x = (m + 0 < M) ? Brow[m + 0] : 0.f;
      b_reg.y = (m + 1 < M) ? Brow[m + 1] : 0.f;
      b_reg.z = (m + 2 < M) ? Brow[m + 2] : 0.f;
      b_reg.w = (m + 3 < M) ? Brow[m + 3] : 0.f;
    }
  }

  float acc[4][4] = {};

  for (int k0 = kstart; k0 < kend; k0 += 16) {
    if (k0 > kstart) __syncthreads();
    As[la_k + 0][la_n] = a_reg.x; As[la_k + 1][la_n] = a_reg.y;
    As[la_k + 2][la_n] = a_reg.z; As[la_k + 3][la_n] = a_reg.w;
    *(float4*)&Bs[lb_k][lb_m] = b_reg;
    __syncthreads();
    if (k0 + 16 < kend) {
      a_reg = *(const float4*)(Arow + (k0 + 16) + la_k);
      int krow = k0 + 16 + lb_k;
      const float* Brow = (krow < split) ? (B1 + (size_t)krow * M)
                                         : (B2 + (size_t)(krow - split) * M);
      int m = m0 + lb_m;
      if (m + 3 < M) b_reg = *(const float4*)(Brow + m);
      else {
        b_reg.x = (m + 0 < M) ? Brow[m + 0] : 0.f;
        b_reg.y = (m + 1 < M) ? Brow[m + 1] : 0.f;
        b_reg.z = (m + 2 < M) ? Brow[m + 2] : 0.f;
        b_reg.w = (m + 3 < M) ? Brow[m + 3] : 0.f;
      }
    }
#pragma unroll
    for (int kk = 0; kk < 16; kk++) {
      float4 av = *(const float4*)&As[kk][tn * 4];
      float4 bv = *(const float4*)&Bs[kk][tm * 4];
      float a[4] = {av.x, av.y, av.z, av.w};
      float b[4] = {bv.x, bv.y, bv.z, bv.w};
#pragma unroll
      for (int i = 0; i < 4; i++)
#pragma unroll
        for (int j = 0; j < 4; j++) acc[i][j] += a[i] * b[j];
    }
  }

  const bool addBias = (blockIdx.z == 0);
#pragma unroll
  for (int i = 0; i < 4; i++) {
    int n = n0 + tn * 4 + i;
    if (n >= N) continue;
#pragma unroll
    for (int j = 0; j < 4; j++) {
      int m = m0 + tm * 4 + j;
      if (m >= M) continue;
      float v = acc[i][j];
      if (addBias && bias1) v += bias1[m];
      if (addBias && bias2) v += bias2[m];
      Cpart[(size_t)n * M + m] = v;
    }
  }
}

// ---- top-k helpers (jax tie-break: value desc, then smaller index) ----
__device__ __forceinline__ bool tk_better(float va, int ia, float vb, int ib) {
  return (va > vb) || (va == vb && ia < ib);
}
__device__ __forceinline__ void tk_insertN(float v, int i, float* vv, int* ii) {
  if (!tk_better(v, i, vv[RT - 1], ii[RT - 1])) return;
  vv[RT - 1] = v; ii[RT - 1] = i;
#pragma unroll
  for (int q = RT - 1; q > 0; q--) {
    if (tk_better(vv[q], ii[q], vv[q - 1], ii[q - 1])) {
      float tv = vv[q]; vv[q] = vv[q - 1]; vv[q - 1] = tv;
      int ti = ii[q]; ii[q] = ii[q - 1]; ii[q - 1] = ti;
    }
  }
}
// merge sorted list (bv2,bi2) into (av,ai), keep RT best
__device__ __forceinline__ void tk_merge_reg(float* av, int* ai,
                                             const float* bv2, const int* bi2) {
  float rv[RT]; int ri[RT];
  int p = 0, q = 0;
#pragma unroll
  for (int t = 0; t < RT; t++) {
    bool ta;
    if (p >= RT) ta = false;
    else if (q >= RT) ta = true;
    else ta = tk_better(av[p], ai[p], bv2[q], bi2[q]);
    if (ta) { rv[t] = av[p]; ri[t] = ai[p]; p++; }
    else    { rv[t] = bv2[q]; ri[t] = bi2[q]; q++; }
  }
#pragma unroll
  for (int t = 0; t < RT; t++) { av[t] = rv[t]; ai[t] = ri[t]; }
}
// LDS pairwise merge
__device__ __forceinline__ void tk_merge_lds(float* sv, int* si, int a, int b) {
  float rv[RT]; int ri[RT];
  int p = 0, q = 0;
#pragma unroll
  for (int t = 0; t < RT; t++) {
    bool ta;
    if (p >= RT) ta = false;
    else if (q >= RT) ta = true;
    else ta = tk_better(sv[a + p], si[a + p], sv[b + q], si[b + q]);
    if (ta) { rv[t] = sv[a + p]; ri[t] = si[a + p]; p++; }
    else    { rv[t] = sv[b + q]; ri[t] = si[b + q]; q++; }
  }
#pragma unroll
  for (int t = 0; t < RT; t++) { sv[a + t] = rv[t]; si[a + t] = ri[t]; }
}

__device__ __forceinline__ float sigf(float x) { return 1.f / (1.f + expf(-x)); }

// ---------------------------------------------------------------------------
// merge of LG_MT per-tile partials for one row -> top-RT + max + lse (LDS out).
// Called by all 256 threads of a block (verified exact in rounds 2-3).
// ---------------------------------------------------------------------------
__device__ void merge_row_dev(int n, int tid,
    const float* __restrict__ ptv, const int* __restrict__ pti,
    const float* __restrict__ pmx, const float* __restrict__ psm,
    float* msv, int* msi, float* mred,
    float* outv, int* outi, float* outM, float* outL)
{
  float mx_t = -3.4e38f, sm_t = 0.f;
  if (tid < 128) {
    float vv[RT]; int ii[RT];
#pragma unroll
    for (int q = 0; q < RT; q++) { vv[q] = -3.4e38f; ii[q] = 0x7fffffff; }
    if (tid < LG_MT) {
      const size_t pb = (size_t)n * LG_MT + tid;
#pragma unroll
      for (int q = 0; q < RT; q++) { vv[q] = ptv[pb * RT + q]; ii[q] = pti[pb * RT + q]; }
      mx_t = pmx[pb]; sm_t = psm[pb];
    }
#pragma unroll
    for (int q = 0; q < RT; q++) { msv[tid * RT + q] = vv[q]; msi[tid * RT + q] = ii[q]; }
  }
  __syncthreads();
  for (int st = 64; st; st >>= 1) {
    if (tid < st) tk_merge_lds(msv, msi, tid * RT, (tid + st) * RT);
    __syncthreads();
  }
  if (tid < 128) mred[tid] = mx_t;
  __syncthreads();
  for (int st = 64; st; st >>= 1) {
    if (tid < st) mred[tid] = fmaxf(mred[tid], mred[tid + st]);
    __syncthreads();
  }
  const float Mg = mred[0];
  __syncthreads();
  if (tid < 128) mred[tid] = sm_t * expf(mx_t - Mg);
  __syncthreads();
  for (int st = 64; st; st >>= 1) {
    if (tid < st) mred[tid] += mred[tid + st];
    __syncthreads();
  }
  if (tid == 0) {
    *outM = Mg; *outL = logf(mred[0]);
#pragma unroll
    for (int q = 0; q < RT; q++) { outv[q] = msv[q]; outi[q] = msi[q]; }
  }
  __syncthreads();
}

// ---------------------------------------------------------------------------
// Fused attention: pp + scores + softmax + ctx for ONE row per block.
// 512 threads. Exact numerics of ppgemv_k/score_k/ctx_k (same partial
// groupings, same reduction trees, same shuffle orders).
// Writes xcat row: [ex | ctx | hprev].
// ---------------------------------------------------------------------------
__global__ __launch_bounds__(512) void attn_k(
    const float* __restrict__ h, const float* __restrict__ encp,
    const float* __restrict__ enc, const float* __restrict__ Wp,
    const float* __restrict__ Wv, const float* __restrict__ mask,
    const float* __restrict__ emb, const int* __restrict__ tok,
    float* __restrict__ xcat, int bdiv, int tok_is_bos)
{
  __shared__ float hS[512];
  __shared__ float ppS[512];
  __shared__ float WvS[512];
  __shared__ float scS[256];
  __shared__ float red[256];
  const int n = blockIdx.x, tid = threadIdx.x;
  const int b = n / bdiv;
  float* xr = xcat + (size_t)n * 1280;

  const float hv = h[(size_t)n * H_ + tid];
  hS[tid] = hv;
  WvS[tid] = Wv[tid];
  xr[E_ + H_ + tid] = hv;                       // hprev
  if (tid < E_) {
    const int tk = tok_is_bos ? BOS_ : tok[n];
    xr[tid] = emb[(size_t)tk * E_ + tid];       // ex
  }
  __syncthreads();

  // pp = h @ Wp — 4 k-chunks of 128 (ascending within chunk), combined
  // left-assoc: matches ppgemv's kg partials + red[tid]+red[64+tid]+... order.
  {
    float p0 = 0.f, p1 = 0.f, p2 = 0.f, p3 = 0.f;
#pragma unroll 4
    for (int kk = 0; kk < 128; kk++) {
      p0 += hS[kk]       * Wp[(size_t)kk * H_ + tid];
      p1 += hS[128 + kk] * Wp[(size_t)(128 + kk) * H_ + tid];
      p2 += hS[256 + kk] * Wp[(size_t)(256 + kk) * H_ + tid];
      p3 += hS[384 + kk] * Wp[(size_t)(384 + kk) * H_ + tid];
    }
    ppS[tid] = p0 + p1 + p2 + p3;
  }
  __syncthreads();

  // scores — identical per-s math to score_k (lane sums r ascending, same
  // shfl_xor tree); warp-to-s assignment differs but each s is independent.
  {
    const int w = tid >> 6, lane = tid & 63;
    for (int s = w; s < S_; s += 8) {
      const float* ep = encp + ((size_t)s * B_ + b) * H_;
      float acc = 0.f;
#pragma unroll
      for (int r = 0; r < 8; r++) {
        const int hh = r * 64 + lane;
        acc += tanhf(ppS[hh] + ep[hh]) * WvS[hh];
      }
#pragma unroll
      for (int off = 32; off; off >>= 1) acc += __shfl_xor(acc, off);
      if (lane == 0)
        scS[s] = (mask[(size_t)b * S_ + s] == 0.f) ? NEG_ : acc;
    }
  }
  __syncthreads();

  // softmax — same 256-slot pairwise trees as ctx_k.
  float v = 0.f;
  if (tid < 256) { v = scS[tid]; red[tid] = v; }
  __syncthreads();
  for (int st = 128; st; st >>= 1) {
    if (tid < st) red[tid] = fmaxf(red[tid], red[tid + st]);
    __syncthreads();
  }
  const float mx = red[0];
  __syncthreads();
  if (tid < 256) { const float e = expf(v - mx); scS[tid] = e; red[tid] = e; }
  __syncthreads();
  for (int st = 128; st; st >>= 1) {
    if (tid < st) red[tid] += red[tid + st];
    __syncthreads();
  }
  const float rsum = 1.f / red[0];
  __syncthreads();

  // ctx — 4 s-mod-4 partials per col (ascending s within group), combined
  // left-assoc: matches ctx_k's sgrp partials + red[tid]+red[64+tid]+... order.
  {
    float c0 = 0.f, c1 = 0.f, c2 = 0.f, c3 = 0.f;
#pragma unroll 2
    for (int s0 = 0; s0 < S_; s0 += 4) {
      c0 += scS[s0 + 0] * enc[((size_t)(s0 + 0) * B_ + b) * H_ + tid];
      c1 += scS[s0 + 1] * enc[((size_t)(s0 + 1) * B_ + b) * H_ + tid];
      c2 += scS[s0 + 2] * enc[((size_t)(s0 + 2) * B_ + b) * H_ + tid];
      c3 += scS[s0 + 3] * enc[((size_t)(s0 + 3) * B_ + b) * H_ + tid];
    }
    xr[E_ + tid] = (c0 + c1 + c2 + c3) * rsum;
  }
}

// ---------------------------------------------------------------------------
// Logits GEMM + fused per-tile top-RT / max / expsum epilogue (verbatim).
// ---------------------------------------------------------------------------
__global__ __launch_bounds__(256) void lggemm_k(
    const float* __restrict__ A, const float* __restrict__ Wc,
    const float* __restrict__ bc, int Nrows,
    float* __restrict__ ptv, int* __restrict__ pti,
    float* __restrict__ pmx, float* __restrict__ psm)
{
  __shared__ float As[16][32];
  __shared__ float Bs[16][128];
  const int tid = threadIdx.x;
  const int mt = blockIdx.x;
  const int m0 = mt * 128;
  const int n0 = blockIdx.y * 32;
  const int tm = tid & 31;
  const int tn = tid >> 5;
  const bool aload = tid < 128;
  const int ar = tid & 31;
  const int ak = ((tid >> 5) & 3) * 4;
  const int arow_idx = (n0 + ar < Nrows) ? (n0 + ar) : 0;
  const float* Arow = A + (size_t)arow_idx * 1280;
  const bool edge = (m0 + 128 > V_);

  float4 a_reg = make_float4(0.f, 0.f, 0.f, 0.f);
  float4 b_reg[2];

  if (aload) a_reg = *(const float4*)(Arow + ak);
#pragma unroll
  for (int l = 0; l < 2; l++) {
    int idx = l * 256 + tid;
    int kr = idx >> 5, c4 = (idx & 31) * 4;
    const float* Brow = Wc + (size_t)kr * V_;
    if (!edge) b_reg[l] = *(const float4*)(Brow + m0 + c4);
    else {
      float4 bv;
      bv.x = (m0 + c4 + 0 < V_) ? Brow[m0 + c4 + 0] : 0.f;
      bv.y = (m0 + c4 + 1 < V_) ? Brow[m0 + c4 + 1] : 0.f;
      bv.z = (m0 + c4 + 2 < V_) ? Brow[m0 + c4 + 2] : 0.f;
      bv.w = (m0 + c4 + 3 < V_) ? Brow[m0 + c4 + 3] : 0.f;
      b_reg[l] = bv;
    }
  }

  float acc[4][4] = {};

  for (int k0 = 0; k0 < 1280; k0 += 16) {
    if (k0 > 0) __syncthreads();
    if (aload) {
      As[ak + 0][ar] = a_reg.x; As[ak + 1][ar] = a_reg.y;
      As[ak + 2][ar] = a_reg.z; As[ak + 3][ar] = a_reg.w;
    }
#pragma unroll
    for (int l = 0; l < 2; l++) {
      int idx = l * 256 + tid;
      int kr = idx >> 5, c4 = (idx & 31) * 4;
      *(float4*)&Bs[kr][c4] = b_reg[l];
    }
    __syncthreads();
    if (k0 + 16 < 1280) {
      if (aload) a_reg = *(const float4*)(Arow + (k0 + 16) + ak);
#pragma unroll
      for (int l = 0; l < 2; l++) {
        int idx = l * 256 + tid;
        int kr = k0 + 16 + (idx >> 5), c4 = (idx & 31) * 4;
        const float* Brow = Wc + (size_t)kr * V_;
        if (!edge) b_reg[l] = *(const float4*)(Brow + m0 + c4);
        else {
          float4 bv;
          bv.x = (m0 + c4 + 0 < V_) ? Brow[m0 + c4 + 0] : 0.f;
          bv.y = (m0 + c4 + 1 < V_) ? Brow[m0 + c4 + 1] : 0.f;
          bv.z = (m0 + c4 + 2 < V_) ? Brow[m0 + c4 + 2] : 0.f;
          bv.w = (m0 + c4 + 3 < V_) ? Brow[m0 + c4 + 3] : 0.f;
          b_reg[l] = bv;
        }
      }
    }
#pragma unroll
    for (int kk = 0; kk < 16; kk++) {
      float4 av = *(const float4*)&As[kk][tn * 4];
      float4 bv = *(const float4*)&Bs[kk][tm * 4];
      float a[4] = {av.x, av.y, av.z, av.w};
      float b[4] = {bv.x, bv.y, bv.z, bv.w};
#pragma unroll
      for (int i = 0; i < 4; i++)
#pragma unroll
        for (int j = 0; j < 4; j++) acc[i][j] += a[i] * b[j];
    }
  }

  // ---- fused epilogue: per-row (of this 128-col tile) top-RT, max, expsum ----
#pragma unroll
  for (int i = 0; i < 4; i++) {
    float vv[RT]; int ii[RT];
#pragma unroll
    for (int q = 0; q < RT; q++) { vv[q] = -3.4e38f; ii[q] = 0x7fffffff; }
    float vals[4];
#pragma unroll
    for (int j = 0; j < 4; j++) {
      int m = m0 + tm * 4 + j;
      float v = (m < V_) ? (acc[i][j] + bc[m]) : -3.4e38f;
      vals[j] = v;
      if (m < V_) tk_insertN(v, m, vv, ii);
    }
    // merge across the 32-lane half-wave (lanes share tn)
#pragma unroll
    for (int off = 1; off < 32; off <<= 1) {
      float ov[RT]; int oi[RT];
#pragma unroll
      for (int q = 0; q < RT; q++) {
        ov[q] = __shfl_xor(vv[q], off);
        oi[q] = __shfl_xor(ii[q], off);
      }
      tk_merge_reg(vv, ii, ov, oi);
    }
    const float rowmax = vv[0];
    float s = 0.f;
#pragma unroll
    for (int j = 0; j < 4; j++) {
      int m = m0 + tm * 4 + j;
      if (m < V_) s += expf(vals[j] - rowmax);
    }
#pragma unroll
    for (int off = 1; off < 32; off <<= 1) s += __shfl_xor(s, off);
    const int gr = n0 + tn * 4 + i;
    if (tm == 0 && gr < Nrows) {
      const size_t pb = (size_t)gr * LG_MT + mt;
#pragma unroll
      for (int q = 0; q < RT; q++) {
        ptv[pb * RT + q] = vv[q]; pti[pb * RT + q] = ii[q];
      }
      pmx[pb] = rowmax;
      psm[pb] = s;
    }
  }
}

// LSTM pointwise; sums 4 split-K gts parts; xcat in place: [ex|ctx|hprev]->[ex|h2|ctx].
__global__ __launch_bounds__(256) void lstm_k(
    const float* __restrict__ gts, const float* __restrict__ cprev,
    float* __restrict__ xcat, float* __restrict__ h2, float* __restrict__ c2)
{
  const int n = blockIdx.x, tid = threadIdx.x;
  float* xr = xcat + (size_t)n * 1280;
  for (int i = tid; i < H_; i += 256) {
    float gi = 0.f, gf = 0.f, gg = 0.f, go = 0.f;
#pragma unroll
    for (int p = 0; p < 4; p++) {
      const float* g = gts + (size_t)p * GST + (size_t)n * (4 * H_);
      gi += g[i]; gf += g[H_ + i]; gg += g[2 * H_ + i]; go += g[3 * H_ + i];
    }
    float ctx_i = xr[E_ + i];
    float cc = cprev[(size_t)n * H_ + i];
    float cv = sigf(gf) * cc + sigf(gi) * tanhf(gg);
    float hv = sigf(go) * tanhf(cv);
    c2[(size_t)n * H_ + i] = cv;
    h2[(size_t)n * H_ + i] = hv;
    xr[E_ + i] = hv;
    xr[E_ + H_ + i] = ctx_i;
  }
}

// ---------------------------------------------------------------------------
// Fused merge + step-0 beam init. grid B_, 256 thr.
// ---------------------------------------------------------------------------
__global__ __launch_bounds__(256) void mreorder0_k(
    const float* __restrict__ h2, const float* __restrict__ c2,
    float* __restrict__ h, float* __restrict__ c,
    const float* __restrict__ ptv, const int* __restrict__ pti,
    const float* __restrict__ pmx, const float* __restrict__ psm,
    float* __restrict__ cum, int* __restrict__ eos, int* __restrict__ tok,
    int* __restrict__ preds)
{
  __shared__ float msv[128 * RT];
  __shared__ int   msi[128 * RT];
  __shared__ float mred[128];
  __shared__ float rmv[RT];
  __shared__ int   rmi[RT];
  __shared__ float rM, rL;
  const int b = blockIdx.x, tid = threadIdx.x;

  merge_row_dev(b, tid, ptv, pti, pmx, psm, msv, msi, mred, rmv, rmi, &rM, &rL);

#pragma unroll
  for (int r = 0; r < K_; r++) {
    const int n = b * K_ + r;
    for (int i = tid; i < H_; i += 256) {
      h[(size_t)n * H_ + i] = h2[(size_t)b * H_ + i];
      c[(size_t)n * H_ + i] = c2[(size_t)b * H_ + i];
    }
    if (tid < T_) preds[tid * N1_ + n] = (tid == 0) ? rmi[r] : 0;
    if (tid == 0) {
      const int idx = rmi[r];
      cum[n] = (rmv[r] - rM) - rL;
      tok[n] = idx;
      eos[n] = (idx == EOS_) ? 1 : 0;
    }
  }
}

// ---------------------------------------------------------------------------
// Fused merge + 12-candidate exact beam select + gather. grid B_, 256 thr.
// (exact port of round-2/3 phase E t>0 branch, verified absmax 0)
// ---------------------------------------------------------------------------
__global__ __launch_bounds__(256) void mreorder1_k(
    const float* __restrict__ h2, const float* __restrict__ c2,
    float* __restrict__ h, float* __restrict__ c,
    const float* __restrict__ ptv, const int* __restrict__ pti,
    const float* __restrict__ pmx, const float* __restrict__ psm,
    const float* __restrict__ cumOld, float* __restrict__ cumNew,
    const int* __restrict__ eosOld, int* __restrict__ eosNew,
    const int* __restrict__ pOld, int* __restrict__ pNew,
    int* __restrict__ tok, int t)
{
  __shared__ float msv[128 * RT];
  __shared__ int   msi[128 * RT];
  __shared__ float mred[128];
  __shared__ float rmv[K_][RT];
  __shared__ int   rmi[K_][RT];
  __shared__ float rM[K_], rL[K_];
  __shared__ float s_val[K_];
  __shared__ int   s_g[K_], s_tok[K_];
  const int b = blockIdx.x, tid = threadIdx.x;

  for (int r = 0; r < K_; r++)
    merge_row_dev(b * K_ + r, tid, ptv, pti, pmx, psm,
                  msv, msi, mred, rmv[r], rmi[r], &rM[r], &rL[r]);

  if (tid == 0) {
    float cv[3 * RT]; int cj[3 * RT]; int cnt = 0;
    for (int k = 0; k < K_; k++) {
      const int row = b * K_ + k;
      const float ck = cumOld[row];
      if (eosOld[row]) {
        cv[cnt] = ck; cj[cnt] = k * V_ + EOS_; cnt++;
      } else {
        const float mxk = rM[k], lsk = rL[k];
        for (int q = 0; q < RT; q++) {
          cv[cnt] = ck + ((rmv[k][q] - mxk) - lsk);
          cj[cnt] = k * V_ + rmi[k][q]; cnt++;
        }
      }
    }
    int used = 0;
    for (int rep = 0; rep < K_; rep++) {
      int pick = -1;
      for (int i2 = 0; i2 < cnt; i2++) {
        if ((used >> i2) & 1) continue;
        if (pick < 0 || tk_better(cv[i2], cj[i2], cv[pick], cj[pick])) pick = i2;
      }
      used |= 1 << pick;
      s_val[rep] = cv[pick];
      s_g[rep] = b * K_ + cj[pick] / V_;
      s_tok[rep] = cj[pick] % V_;
    }
  }
  __syncthreads();
#pragma unroll
  for (int r = 0; r < K_; r++) {
    const int n = b * K_ + r;
    const int g = s_g[r], ntok = s_tok[r];
    for (int i = tid; i < H_; i += 256) {
      h[(size_t)n * H_ + i] = h2[(size_t)g * H_ + i];
      c[(size_t)n * H_ + i] = c2[(size_t)g * H_ + i];
    }
    if (tid < T_) pNew[tid * N1_ + n] = (tid == t) ? ntok : pOld[tid * N1_ + g];
    if (tid == 0) {
      cumNew[n] = s_val[r];
      eosNew[n] = eosOld[g] | ((ntok == EOS_) ? 1 : 0);
      tok[n] = ntok;
    }
  }
}

__global__ __launch_bounds__(256) void finalout_k(
    const int* __restrict__ preds, const float* __restrict__ cum,
    float* __restrict__ out)
{
  const int i = blockIdx.x * 256 + threadIdx.x;
  if (i < T_ * B_) {
    int t = i >> 5, b = i & 31;
    out[i] = (float)preds[t * N1_ + b * K_];
  } else if (i < T_ * B_ + N1_) {
    out[i] = cum[i - T_ * B_];
  }
}

// ---------------------------------------------------------------------------
extern "C" void kernel_launch(void* const* d_in, const int* in_sizes, int n_in,
                              void* d_out, int out_size, void* d_ws, size_t ws_size,
                              hipStream_t stream)
{
  const float* enc    = (const float*)d_in[0];
  const float* last_h = (const float*)d_in[1];
  const float* last_c = (const float*)d_in[2];
  const float* mask   = (const float*)d_in[3];
  const float* emb    = (const float*)d_in[5];
  const float* Wp     = (const float*)d_in[6];
  const float* We     = (const float*)d_in[7];
  const float* Wv     = (const float*)d_in[8];
  const float* W_ih   = (const float*)d_in[9];
  const float* W_hh   = (const float*)d_in[10];
  const float* b_ih   = (const float*)d_in[11];
  const float* b_hh   = (const float*)d_in[12];
  const float* Wc     = (const float*)d_in[13];
  const float* bc     = (const float*)d_in[14];
  const float* W_init = (const float*)d_in[15];
  const float* b_init = (const float*)d_in[16];

  // ws carve — ~21.4 MB (< proven 23.69 MB)
  float* w = (float*)d_ws;
  float* encp = w;  w += (size_t)S_ * B_ * H_;   // 16.78 MB
  float* h    = w;  w += N1_ * H_;
  float* c    = w;  w += N1_ * H_;
  float* h2   = w;  w += N1_ * H_;
  float* c2   = w;  w += N1_ * H_;
  float* xcat = w;  w += N1_ * 1280;             // doubles as x2 (in-place LSTM)
  float* gts  = w;  w += 4 * GST;                // 4 split-K parts
  float* ptv  = w;  w += (size_t)N1_ * LG_MT * RT;
  float* pmx  = w;  w += (size_t)N1_ * LG_MT;
  float* psm  = w;  w += (size_t)N1_ * LG_MT;
  float* cumA = w;  w += N1_;
  float* cumB = w;  w += N1_;
  int* pti  = (int*)w;  w += (size_t)N1_ * LG_MT * RT;
  int* tok  = (int*)w;  w += N1_;
  int* eosA = (int*)w;  w += N1_;
  int* eosB = (int*)w;  w += N1_;
  int* pA   = (int*)w;  w += T_ * N1_;
  int* pB   = (int*)w;  w += T_ * N1_;

  // ---- prologue ----
  gemm_k<<<dim3(8, 1, 1), 256, 0, stream>>>(last_h + B_ * H_, W_init, nullptr, H_,
      b_init, nullptr, h, B_, H_, H_, H_, 0);
  gemm_k<<<dim3(8, 1, 1), 256, 0, stream>>>(last_c + B_ * H_, W_init, nullptr, H_,
      b_init, nullptr, c, B_, H_, H_, H_, 0);
  gemm_k<<<dim3(8, 128, 1), 256, 0, stream>>>(enc, We, nullptr, H_,
      nullptr, nullptr, encp, S_ * B_, H_, H_, H_, 0);

  for (int t = 0; t < T_; t++) {
    const int N = (t == 0) ? B_ : N1_;
    const int ntiles = (t == 0) ? 1 : 2;         // 64-row tiles for gts gemm
    const int nt32 = (t == 0) ? 1 : 3;           // 32-row tiles for logits gemm
    const int bdiv = (t == 0) ? 1 : K_;

    attn_k<<<N, 512, 0, stream>>>(h, encp, enc, Wp, Wv, mask, emb, tok,
        xcat, bdiv, t == 0 ? 1 : 0);
    gemm_k<<<dim3(32, ntiles, 4), 256, 0, stream>>>(xcat, W_ih, W_hh, E_ + H_,
        b_ih, b_hh, gts, N, 1280, 4 * H_, 320, GST);
    lstm_k<<<N, 256, 0, stream>>>(gts, c, xcat, h2, c2);
    lggemm_k<<<dim3(LG_MT, nt32), 256, 0, stream>>>(xcat, Wc, bc, N,
        ptv, pti, pmx, psm);
    if (t == 0) {
      mreorder0_k<<<B_, 256, 0, stream>>>(h2, c2, h, c, ptv, pti, pmx, psm,
          cumA, eosA, tok, pA);
    } else {
      float* cumOld = (t & 1) ? cumA : cumB;
      float* cumNew = (t & 1) ? cumB : cumA;
      int* eosOld = (t & 1) ? eosA : eosB;
      int* eosNew = (t & 1) ? eosB : eosA;
      int* pOld   = (t & 1) ? pA : pB;
      int* pNew   = (t & 1) ? pB : pA;
      mreorder1_k<<<B_, 256, 0, stream>>>(h2, c2, h, c, ptv, pti, pmx, psm,
          cumOld, cumNew, eosOld, eosNew, pOld, pNew, tok, t);
    }
  }

  // t=31 odd -> preds in pB, cum in cumB
  finalout_k<<<5, 256, 0, stream>>>(pB, cumB, (float*)d_out);
}

// Round 5
// 5722.211 us; speedup vs baseline: 2.7170x; 1.7902x over previous
//
#include <hip/hip_runtime.h>
#include <math.h>

#define S_   256
#define B_   32
#define H_   512
#define E_   256
#define V_   10000
#define K_   3
#define T_   32
#define N1_  96
#define BOS_ 1
#define EOS_ 1
#define NEG_ (-1000000000.0f)
#define RT   4        // per-row top-RT kept for exact beam merge (RT > K suffices)
#define LG_MT 79      // ceil(10000/128) m-tiles in logits GEMM
#define GST  (N1_ * 4 * H_)   // gts part stride (floats)

// ---------------------------------------------------------------------------
// Generic fp32 tiled GEMM (prologue + gts): 64x64 tile, TK=16, 256 thr, 4x4
// thread tile, register-prefetch double buffering, split-K via blockIdx.z.
// ---------------------------------------------------------------------------
__global__ __launch_bounds__(256) void gemm_k(
    const float* __restrict__ A, const float* __restrict__ B1,
    const float* __restrict__ B2, int split,
    const float* __restrict__ bias1, const float* __restrict__ bias2,
    float* __restrict__ C, int N, int Kd, int M, int klen, size_t cstride)
{
  __shared__ float As[16][64];
  __shared__ float Bs[16][64];
  const int tid = threadIdx.x;
  const int m0 = blockIdx.x * 64;
  const int n0 = blockIdx.y * 64;
  const int kstart = blockIdx.z * klen;
  const int kend = kstart + klen;
  const int tm = tid & 15, tn = tid >> 4;
  const int la_n = tid & 63;
  const int la_k = (tid >> 6) * 4;
  const int lb_m = (tid & 15) * 4;
  const int lb_k = tid >> 4;

  const int an = (n0 + la_n < N) ? (n0 + la_n) : 0;   // clamp (store guarded)
  const float* Arow = A + (size_t)an * Kd;
  float* Cpart = C + (size_t)blockIdx.z * cstride;

  float4 a_reg, b_reg;
  a_reg = *(const float4*)(Arow + kstart + la_k);
  {
    int krow = kstart + lb_k;
    const float* Brow = (krow < split) ? (B1 + (size_t)krow * M)
                                       : (B2 + (size_t)(krow - split) * M);
    int m = m0 + lb_m;
    if (m + 3 < M) b_reg = *(const float4*)(Brow + m);
    else {
      b_reg.x = (m + 0 < M) ? Brow[m + 0] : 0.f;
      b_reg.y = (m + 1 < M) ? Brow[m + 1] : 0.f;
      b_reg.z = (m + 2 < M) ? Brow[m + 2] : 0.f;
      b_reg.w = (m + 3 < M) ? Brow[m + 3] : 0.f;
    }
  }

  float acc[4][4] = {};

  for (int k0 = kstart; k0 < kend; k0 += 16) {
    if (k0 > kstart) __syncthreads();
    As[la_k + 0][la_n] = a_reg.x; As[la_k + 1][la_n] = a_reg.y;
    As[la_k + 2][la_n] = a_reg.z; As[la_k + 3][la_n] = a_reg.w;
    *(float4*)&Bs[lb_k][lb_m] = b_reg;
    __syncthreads();
    if (k0 + 16 < kend) {
      a_reg = *(const float4*)(Arow + (k0 + 16) + la_k);
      int krow = k0 + 16 + lb_k;
      const float* Brow = (krow < split) ? (B1 + (size_t)krow * M)
                                         : (B2 + (size_t)(krow - split) * M);
      int m = m0 + lb_m;
      if (m + 3 < M) b_reg = *(const float4*)(Brow + m);
      else {
        b_reg.x = (m + 0 < M) ? Brow[m + 0] : 0.f;
        b_reg.y = (m + 1 < M) ? Brow[m + 1] : 0.f;
        b_reg.z = (m + 2 < M) ? Brow[m + 2] : 0.f;
        b_reg.w = (m + 3 < M) ? Brow[m + 3] : 0.f;
      }
    }
#pragma unroll
    for (int kk = 0; kk < 16; kk++) {
      float4 av = *(const float4*)&As[kk][tn * 4];
      float4 bv = *(const float4*)&Bs[kk][tm * 4];
      float a[4] = {av.x, av.y, av.z, av.w};
      float b[4] = {bv.x, bv.y, bv.z, bv.w};
#pragma unroll
      for (int i = 0; i < 4; i++)
#pragma unroll
        for (int j = 0; j < 4; j++) acc[i][j] += a[i] * b[j];
    }
  }

  const bool addBias = (blockIdx.z == 0);
#pragma unroll
  for (int i = 0; i < 4; i++) {
    int n = n0 + tn * 4 + i;
    if (n >= N) continue;
#pragma unroll
    for (int j = 0; j < 4; j++) {
      int m = m0 + tm * 4 + j;
      if (m >= M) continue;
      float v = acc[i][j];
      if (addBias && bias1) v += bias1[m];
      if (addBias && bias2) v += bias2[m];
      Cpart[(size_t)n * M + m] = v;
    }
  }
}

// ---- top-k helpers (jax tie-break: value desc, then smaller index) ----
__device__ __forceinline__ bool tk_better(float va, int ia, float vb, int ib) {
  return (va > vb) || (va == vb && ia < ib);
}
__device__ __forceinline__ void tk_insertN(float v, int i, float* vv, int* ii) {
  if (!tk_better(v, i, vv[RT - 1], ii[RT - 1])) return;
  vv[RT - 1] = v; ii[RT - 1] = i;
#pragma unroll
  for (int q = RT - 1; q > 0; q--) {
    if (tk_better(vv[q], ii[q], vv[q - 1], ii[q - 1])) {
      float tv = vv[q]; vv[q] = vv[q - 1]; vv[q - 1] = tv;
      int ti = ii[q]; ii[q] = ii[q - 1]; ii[q - 1] = ti;
    }
  }
}
// merge sorted list (bv2,bi2) into (av,ai), keep RT best
__device__ __forceinline__ void tk_merge_reg(float* av, int* ai,
                                             const float* bv2, const int* bi2) {
  float rv[RT]; int ri[RT];
  int p = 0, q = 0;
#pragma unroll
  for (int t = 0; t < RT; t++) {
    bool ta;
    if (p >= RT) ta = false;
    else if (q >= RT) ta = true;
    else ta = tk_better(av[p], ai[p], bv2[q], bi2[q]);
    if (ta) { rv[t] = av[p]; ri[t] = ai[p]; p++; }
    else    { rv[t] = bv2[q]; ri[t] = bi2[q]; q++; }
  }
#pragma unroll
  for (int t = 0; t < RT; t++) { av[t] = rv[t]; ai[t] = ri[t]; }
}
// LDS pairwise merge (used by lgmerge_k)
__device__ __forceinline__ void tk_merge_lds(float* sv, int* si, int a, int b) {
  float rv[RT]; int ri[RT];
  int p = 0, q = 0;
#pragma unroll
  for (int t = 0; t < RT; t++) {
    bool ta;
    if (p >= RT) ta = false;
    else if (q >= RT) ta = true;
    else ta = tk_better(sv[a + p], si[a + p], sv[b + q], si[b + q]);
    if (ta) { rv[t] = sv[a + p]; ri[t] = si[a + p]; p++; }
    else    { rv[t] = sv[b + q]; ri[t] = si[b + q]; q++; }
  }
#pragma unroll
  for (int t = 0; t < RT; t++) { sv[a + t] = rv[t]; si[a + t] = ri[t]; }
}

// ---------------------------------------------------------------------------
// Logits GEMM, producer-consumer: 512 threads. Waves 0-3 (tid<256) run the
// VERBATIM baseline compute + fused top-RT epilogue (bit-identical FMA chains
// and reduction trees). Waves 4-7 are loaders filling double-buffered LDS one
// K-step ahead, hiding global latency under the compute phase.
// Tile 32 rows x 128 cols, grid (LG_MT, ceil(Nrows/32)).
// ---------------------------------------------------------------------------
__global__ __launch_bounds__(512) void lggemm_k(
    const float* __restrict__ A, const float* __restrict__ Wc,
    const float* __restrict__ bc, int Nrows,
    float* __restrict__ ptv, int* __restrict__ pti,
    float* __restrict__ pmx, float* __restrict__ psm)
{
  __shared__ float As[2][16][32];
  __shared__ float Bs[2][16][128];
  const int tid = threadIdx.x;
  const int mt = blockIdx.x;
  const int m0 = mt * 128;
  const int n0 = blockIdx.y * 32;
  const bool edge = (m0 + 128 > V_);

  if (tid < 256) {
    // -------- compute role: arithmetic verbatim from verified baseline -----
    const int tm = tid & 31;
    const int tn = tid >> 5;
    float acc[4][4] = {};

    for (int it = 0; it < 80; it++) {
      __syncthreads();                       // buf[it&1] ready
      const int cur = it & 1;
#pragma unroll
      for (int kk = 0; kk < 16; kk++) {
        float4 av = *(const float4*)&As[cur][kk][tn * 4];
        float4 bv = *(const float4*)&Bs[cur][kk][tm * 4];
        float a[4] = {av.x, av.y, av.z, av.w};
        float b[4] = {bv.x, bv.y, bv.z, bv.w};
#pragma unroll
        for (int i = 0; i < 4; i++)
#pragma unroll
          for (int j = 0; j < 4; j++) acc[i][j] += a[i] * b[j];
      }
    }

    // ---- fused epilogue: per-row (of this 128-col tile) top-RT, max, expsum
#pragma unroll
    for (int i = 0; i < 4; i++) {
      float vv[RT]; int ii[RT];
#pragma unroll
      for (int q = 0; q < RT; q++) { vv[q] = -3.4e38f; ii[q] = 0x7fffffff; }
      float vals[4];
#pragma unroll
      for (int j = 0; j < 4; j++) {
        int m = m0 + tm * 4 + j;
        float v = (m < V_) ? (acc[i][j] + bc[m]) : -3.4e38f;
        vals[j] = v;
        if (m < V_) tk_insertN(v, m, vv, ii);
      }
      // merge across the 32-lane half-wave (lanes share tn)
#pragma unroll
      for (int off = 1; off < 32; off <<= 1) {
        float ov[RT]; int oi[RT];
#pragma unroll
        for (int q = 0; q < RT; q++) {
          ov[q] = __shfl_xor(vv[q], off);
          oi[q] = __shfl_xor(ii[q], off);
        }
        tk_merge_reg(vv, ii, ov, oi);
      }
      const float rowmax = vv[0];
      float s = 0.f;
#pragma unroll
      for (int j = 0; j < 4; j++) {
        int m = m0 + tm * 4 + j;
        if (m < V_) s += expf(vals[j] - rowmax);
      }
#pragma unroll
      for (int off = 1; off < 32; off <<= 1) s += __shfl_xor(s, off);
      const int gr = n0 + tn * 4 + i;
      if (tm == 0 && gr < Nrows) {
        const size_t pb = (size_t)gr * LG_MT + mt;
#pragma unroll
        for (int q = 0; q < RT; q++) {
          ptv[pb * RT + q] = vv[q]; pti[pb * RT + q] = ii[q];
        }
        pmx[pb] = rowmax;
        psm[pb] = s;
      }
    }
  } else {
    // -------- loader role: fill buf[(it+1)&1] one K-step ahead -------------
    const int t2 = tid - 256;
    const bool aload = t2 < 128;
    const int ar = t2 & 31;
    const int ak = ((t2 >> 5) & 3) * 4;
    const int arow_idx = (n0 + ar < Nrows) ? (n0 + ar) : 0;
    const float* Arow = A + (size_t)arow_idx * 1280;

    float4 a_reg = make_float4(0.f, 0.f, 0.f, 0.f);
    float4 b_reg[2];

    // prologue: chunk 0 -> buf 0 (before first barrier)
    if (aload) a_reg = *(const float4*)(Arow + ak);
#pragma unroll
    for (int l = 0; l < 2; l++) {
      int idx = l * 256 + t2;
      int kr = idx >> 5, c4 = (idx & 31) * 4;
      const float* Brow = Wc + (size_t)kr * V_;
      if (!edge) b_reg[l] = *(const float4*)(Brow + m0 + c4);
      else {
        float4 bv;
        bv.x = (m0 + c4 + 0 < V_) ? Brow[m0 + c4 + 0] : 0.f;
        bv.y = (m0 + c4 + 1 < V_) ? Brow[m0 + c4 + 1] : 0.f;
        bv.z = (m0 + c4 + 2 < V_) ? Brow[m0 + c4 + 2] : 0.f;
        bv.w = (m0 + c4 + 3 < V_) ? Brow[m0 + c4 + 3] : 0.f;
        b_reg[l] = bv;
      }
    }
    if (aload) {
      As[0][ak + 0][ar] = a_reg.x; As[0][ak + 1][ar] = a_reg.y;
      As[0][ak + 2][ar] = a_reg.z; As[0][ak + 3][ar] = a_reg.w;
    }
#pragma unroll
    for (int l = 0; l < 2; l++) {
      int idx = l * 256 + t2;
      int kr = idx >> 5, c4 = (idx & 31) * 4;
      *(float4*)&Bs[0][kr][c4] = b_reg[l];
    }

    for (int it = 0; it < 80; it++) {
      __syncthreads();                       // compute starts on buf[it&1]
      if (it + 1 < 80) {
        const int kb = (it + 1) * 16;
        const int nb2 = (it + 1) & 1;
        if (aload) a_reg = *(const float4*)(Arow + kb + ak);
#pragma unroll
        for (int l = 0; l < 2; l++) {
          int idx = l * 256 + t2;
          int kr = kb + (idx >> 5), c4 = (idx & 31) * 4;
          const float* Brow = Wc + (size_t)kr * V_;
          if (!edge) b_reg[l] = *(const float4*)(Brow + m0 + c4);
          else {
            float4 bv;
            bv.x = (m0 + c4 + 0 < V_) ? Brow[m0 + c4 + 0] : 0.f;
            bv.y = (m0 + c4 + 1 < V_) ? Brow[m0 + c4 + 1] : 0.f;
            bv.z = (m0 + c4 + 2 < V_) ? Brow[m0 + c4 + 2] : 0.f;
            bv.w = (m0 + c4 + 3 < V_) ? Brow[m0 + c4 + 3] : 0.f;
            b_reg[l] = bv;
          }
        }
        if (aload) {
          As[nb2][ak + 0][ar] = a_reg.x; As[nb2][ak + 1][ar] = a_reg.y;
          As[nb2][ak + 2][ar] = a_reg.z; As[nb2][ak + 3][ar] = a_reg.w;
        }
#pragma unroll
        for (int l = 0; l < 2; l++) {
          int idx = l * 256 + t2;
          int kr = idx >> 5, c4 = (idx & 31) * 4;
          *(float4*)&Bs[nb2][kr][c4] = b_reg[l];
        }
      }
    }
  }
}

// Merge LG_MT per-tile partials per row -> rtv/rti/rmax/rlse. grid Nrows, 128 thr.
__global__ __launch_bounds__(128) void lgmerge_k(
    const float* __restrict__ ptv, const int* __restrict__ pti,
    const float* __restrict__ pmx, const float* __restrict__ psm,
    float* __restrict__ rtv, int* __restrict__ rti,
    float* __restrict__ rmax, float* __restrict__ rlse)
{
  __shared__ float sv[128 * RT];
  __shared__ int si[128 * RT];
  __shared__ float red[128];
  const int n = blockIdx.x, tid = threadIdx.x;
  float mx_t = -3.4e38f, sm_t = 0.f;
  float vv[RT]; int ii[RT];
#pragma unroll
  for (int q = 0; q < RT; q++) { vv[q] = -3.4e38f; ii[q] = 0x7fffffff; }
  if (tid < LG_MT) {
    const size_t pb = (size_t)n * LG_MT + tid;
#pragma unroll
    for (int q = 0; q < RT; q++) { vv[q] = ptv[pb * RT + q]; ii[q] = pti[pb * RT + q]; }
    mx_t = pmx[pb]; sm_t = psm[pb];
  }
#pragma unroll
  for (int q = 0; q < RT; q++) { sv[tid * RT + q] = vv[q]; si[tid * RT + q] = ii[q]; }
  __syncthreads();
  for (int st = 64; st; st >>= 1) {
    if (tid < st) tk_merge_lds(sv, si, tid * RT, (tid + st) * RT);
    __syncthreads();
  }
  red[tid] = mx_t; __syncthreads();
  for (int st = 64; st; st >>= 1) {
    if (tid < st) red[tid] = fmaxf(red[tid], red[tid + st]);
    __syncthreads();
  }
  const float Mg = red[0]; __syncthreads();
  red[tid] = sm_t * expf(mx_t - Mg); __syncthreads();
  for (int st = 64; st; st >>= 1) {
    if (tid < st) red[tid] += red[tid + st];
    __syncthreads();
  }
  if (tid < RT) { rtv[n * RT + tid] = sv[tid]; rti[n * RT + tid] = si[tid]; }
  if (tid == 0) { rmax[n] = Mg; rlse[n] = logf(red[0]); }
}

// ---------------------------------------------------------------------------
// pp[n][m0..m0+63] = sum_k h[n][k] * Wp[k][m].  grid (8, N), 256 thr.
// ---------------------------------------------------------------------------
__global__ __launch_bounds__(256) void ppgemv_k(
    const float* __restrict__ h, const float* __restrict__ Wp,
    float* __restrict__ pp)
{
  __shared__ float hS[512];
  __shared__ float red[256];
  const int n = blockIdx.y, tid = threadIdx.x;
  const int m = blockIdx.x * 64 + (tid & 63);
  const int kg = tid >> 6;
  hS[tid] = h[(size_t)n * H_ + tid];
  hS[256 + tid] = h[(size_t)n * H_ + 256 + tid];
  __syncthreads();
  float acc = 0.f;
#pragma unroll 4
  for (int k = kg * 128; k < kg * 128 + 128; k++)
    acc += hS[k] * Wp[(size_t)k * H_ + m];
  red[tid] = acc;
  __syncthreads();
  if (tid < 64) {
    float v = red[tid] + red[64 + tid] + red[128 + tid] + red[192 + tid];
    pp[(size_t)n * H_ + blockIdx.x * 64 + tid] = v;
  }
}

// ---------------------------------------------------------------------------
// Raw masked scores; stile 0 also fills xcat[ex | .. | hprev].
// grid (8 s-tiles, N), 512 thr.
// ---------------------------------------------------------------------------
__global__ __launch_bounds__(512) void score_k(
    const float* __restrict__ pp, const float* __restrict__ encp,
    const float* __restrict__ Wv, const float* __restrict__ mask,
    const float* __restrict__ emb, const int* __restrict__ tok,
    const float* __restrict__ h, float* __restrict__ sc,
    float* __restrict__ xcat, int bdiv, int tok_is_bos)
{
  __shared__ float ppS[512];
  __shared__ float WvS[512];
  const int n = blockIdx.y, tid = threadIdx.x;
  const int b = n / bdiv;
  ppS[tid] = pp[(size_t)n * H_ + tid];
  WvS[tid] = Wv[tid];
  if (blockIdx.x == 0) {
    xcat[(size_t)n * 1280 + E_ + H_ + tid] = h[(size_t)n * H_ + tid];  // hprev
    if (tid < E_) {
      int tk = tok_is_bos ? BOS_ : tok[n];
      xcat[(size_t)n * 1280 + tid] = emb[(size_t)tk * E_ + tid];       // ex
    }
  }
  __syncthreads();
  const int w = tid >> 6, lane = tid & 63;
#pragma unroll
  for (int j = 0; j < 4; j++) {
    int s = blockIdx.x * 32 + w * 4 + j;
    const float* ep = encp + ((size_t)s * B_ + b) * H_;
    float acc = 0.f;
#pragma unroll
    for (int r = 0; r < 8; r++) {
      int hh = r * 64 + lane;
      acc += tanhf(ppS[hh] + ep[hh]) * WvS[hh];
    }
#pragma unroll
    for (int off = 32; off; off >>= 1) acc += __shfl_xor(acc, off);
    if (lane == 0)
      sc[(size_t)n * S_ + s] = (mask[(size_t)b * S_ + s] == 0.f) ? NEG_ : acc;
  }
}

// ---------------------------------------------------------------------------
// ctx slice with in-block softmax recompute. grid (8 h-tiles, N), 256 thr.
// ---------------------------------------------------------------------------
__global__ __launch_bounds__(256) void ctx_k(
    const float* __restrict__ sc, const float* __restrict__ enc,
    float* __restrict__ xcat, int bdiv)
{
  __shared__ float aS[256];
  __shared__ float red[256];
  const int n = blockIdx.y, tid = threadIdx.x;
  const int b = n / bdiv;
  const int h0 = blockIdx.x * 64;
  float v = sc[(size_t)n * S_ + tid];
  red[tid] = v; __syncthreads();
  for (int st = 128; st; st >>= 1) {
    if (tid < st) red[tid] = fmaxf(red[tid], red[tid + st]);
    __syncthreads();
  }
  const float mx = red[0]; __syncthreads();
  float e = expf(v - mx);
  aS[tid] = e;
  red[tid] = e; __syncthreads();
  for (int st = 128; st; st >>= 1) {
    if (tid < st) red[tid] += red[tid + st];
    __syncthreads();
  }
  const float rsum = 1.f / red[0];
  __syncthreads();
  const int sgrp = tid >> 6, col = tid & 63;
  float acc = 0.f;
#pragma unroll 4
  for (int s0 = 0; s0 < S_; s0 += 4) {
    int s = s0 + sgrp;
    acc += aS[s] * enc[((size_t)s * B_ + b) * H_ + h0 + col];
  }
  red[tid] = acc; __syncthreads();
  if (tid < 64) {
    float total = red[tid] + red[64 + tid] + red[128 + tid] + red[192 + tid];
    xcat[(size_t)n * 1280 + E_ + h0 + tid] = total * rsum;
  }
}

__device__ __forceinline__ float sigf(float x) { return 1.f / (1.f + expf(-x)); }

// LSTM pointwise; sums 4 split-K gts parts; xcat in place: [ex|ctx|hprev]->[ex|h2|ctx].
__global__ __launch_bounds__(256) void lstm_k(
    const float* __restrict__ gts, const float* __restrict__ cprev,
    float* __restrict__ xcat, float* __restrict__ h2, float* __restrict__ c2)
{
  const int n = blockIdx.x, tid = threadIdx.x;
  float* xr = xcat + (size_t)n * 1280;
  for (int i = tid; i < H_; i += 256) {
    float gi = 0.f, gf = 0.f, gg = 0.f, go = 0.f;
#pragma unroll
    for (int p = 0; p < 4; p++) {
      const float* g = gts + (size_t)p * GST + (size_t)n * (4 * H_);
      gi += g[i]; gf += g[H_ + i]; gg += g[2 * H_ + i]; go += g[3 * H_ + i];
    }
    float ctx_i = xr[E_ + i];
    float cc = cprev[(size_t)n * H_ + i];
    float cv = sigf(gf) * cc + sigf(gi) * tanhf(gg);
    float hv = sigf(go) * tanhf(cv);
    c2[(size_t)n * H_ + i] = cv;
    h2[(size_t)n * H_ + i] = hv;
    xr[E_ + i] = hv;
    xr[E_ + H_ + i] = ctx_i;
  }
}

// step-0: beam expand + init. grid 96.
__global__ __launch_bounds__(256) void reorder0_k(
    const float* __restrict__ h2, const float* __restrict__ c2,
    float* __restrict__ h, float* __restrict__ c,
    const float* __restrict__ rtv, const int* __restrict__ rti,
    const float* __restrict__ rmax, const float* __restrict__ rlse,
    float* __restrict__ cum, int* __restrict__ eos, int* __restrict__ tok,
    int* __restrict__ preds)
{
  const int n = blockIdx.x, b = n / K_, r = n % K_, tid = threadIdx.x;
  for (int i = tid; i < H_; i += 256) {
    h[(size_t)n * H_ + i] = h2[(size_t)b * H_ + i];
    c[(size_t)n * H_ + i] = c2[(size_t)b * H_ + i];
  }
  if (tid < T_) preds[tid * N1_ + n] = 0;
  if (tid == 0) {
    float val = (rtv[b * RT + r] - rmax[b]) - rlse[b];
    int idx = rti[b * RT + r];
    preds[n] = idx;
    cum[n] = val; tok[n] = idx; eos[n] = (idx == EOS_) ? 1 : 0;
  }
}

// step-t: 12-candidate exact merge + gather. grid 96.
__global__ __launch_bounds__(256) void reorder1_k(
    const float* __restrict__ h2, const float* __restrict__ c2,
    float* __restrict__ h, float* __restrict__ c,
    const float* __restrict__ rtv, const int* __restrict__ rti,
    const float* __restrict__ rmax, const float* __restrict__ rlse,
    const float* __restrict__ cumOld, float* __restrict__ cumNew,
    const int* __restrict__ eosOld, int* __restrict__ eosNew,
    const int* __restrict__ pOld, int* __restrict__ pNew,
    int* __restrict__ tok, int t)
{
  __shared__ int s_g, s_tok;
  __shared__ float s_val;
  const int n = blockIdx.x, b = n / K_, r = n % K_, tid = threadIdx.x;
  if (tid == 0) {
    float cv[3 * RT]; int cj[3 * RT]; int cnt = 0;
    for (int k = 0; k < K_; k++) {
      int row = b * K_ + k;
      float ck = cumOld[row];
      if (eosOld[row]) {
        cv[cnt] = ck; cj[cnt] = k * V_ + EOS_; cnt++;
      } else {
        float mxk = rmax[row], lsk = rlse[row];
        for (int q = 0; q < RT; q++) {
          cv[cnt] = ck + ((rtv[row * RT + q] - mxk) - lsk);
          cj[cnt] = k * V_ + rti[row * RT + q]; cnt++;
        }
      }
    }
    int used = 0, pick = -1;
    for (int rep = 0; rep <= r; rep++) {
      pick = -1;
      for (int i2 = 0; i2 < cnt; i2++) {
        if ((used >> i2) & 1) continue;
        if (pick < 0 || tk_better(cv[i2], cj[i2], cv[pick], cj[pick])) pick = i2;
      }
      used |= 1 << pick;
    }
    int j = cj[pick];
    s_val = cv[pick];
    s_g = b * K_ + j / V_;
    s_tok = j % V_;
  }
  __syncthreads();
  const int g = s_g, ntok = s_tok;
  for (int i = tid; i < H_; i += 256) {
    h[(size_t)n * H_ + i] = h2[(size_t)g * H_ + i];
    c[(size_t)n * H_ + i] = c2[(size_t)g * H_ + i];
  }
  if (tid < T_) pNew[tid * N1_ + n] = (tid == t) ? ntok : pOld[tid * N1_ + g];
  if (tid == 0) {
    cumNew[n] = s_val;
    eosNew[n] = eosOld[g] | (ntok == EOS_ ? 1 : 0);
    tok[n] = ntok;
  }
}

__global__ __launch_bounds__(256) void finalout_k(
    const int* __restrict__ preds, const float* __restrict__ cum,
    float* __restrict__ out)
{
  const int i = blockIdx.x * 256 + threadIdx.x;
  if (i < T_ * B_) {
    int t = i >> 5, b = i & 31;
    out[i] = (float)preds[t * N1_ + b * K_];
  } else if (i < T_ * B_ + N1_) {
    out[i] = cum[i - T_ * B_];
  }
}

// ---------------------------------------------------------------------------
extern "C" void kernel_launch(void* const* d_in, const int* in_sizes, int n_in,
                              void* d_out, int out_size, void* d_ws, size_t ws_size,
                              hipStream_t stream)
{
  const float* enc    = (const float*)d_in[0];
  const float* last_h = (const float*)d_in[1];
  const float* last_c = (const float*)d_in[2];
  const float* mask   = (const float*)d_in[3];
  const float* emb    = (const float*)d_in[5];
  const float* Wp     = (const float*)d_in[6];
  const float* We     = (const float*)d_in[7];
  const float* Wv     = (const float*)d_in[8];
  const float* W_ih   = (const float*)d_in[9];
  const float* W_hh   = (const float*)d_in[10];
  const float* b_ih   = (const float*)d_in[11];
  const float* b_hh   = (const float*)d_in[12];
  const float* Wc     = (const float*)d_in[13];
  const float* bc     = (const float*)d_in[14];
  const float* W_init = (const float*)d_in[15];
  const float* b_init = (const float*)d_in[16];

  // ws carve — unconditional footprint ~21.8 MB (< proven 23.69 MB)
  float* w = (float*)d_ws;
  float* encp = w;  w += (size_t)S_ * B_ * H_;   // 16.78 MB
  float* h    = w;  w += N1_ * H_;
  float* c    = w;  w += N1_ * H_;
  float* h2   = w;  w += N1_ * H_;
  float* c2   = w;  w += N1_ * H_;
  float* pp   = w;  w += N1_ * H_;
  float* sc   = w;  w += N1_ * S_;
  float* xcat = w;  w += N1_ * 1280;             // doubles as x2 (in-place LSTM)
  float* gts  = w;  w += 4 * GST;                // 4 split-K parts
  float* ptv  = w;  w += (size_t)N1_ * LG_MT * RT;
  float* pmx  = w;  w += (size_t)N1_ * LG_MT;
  float* psm  = w;  w += (size_t)N1_ * LG_MT;
  float* rtv  = w;  w += N1_ * RT;
  float* rmax = w;  w += N1_;
  float* rlse = w;  w += N1_;
  float* cumA = w;  w += N1_;
  float* cumB = w;  w += N1_;
  int* pti  = (int*)w;  w += (size_t)N1_ * LG_MT * RT;
  int* rti  = (int*)w;  w += N1_ * RT;
  int* tok  = (int*)w;  w += N1_;
  int* eosA = (int*)w;  w += N1_;
  int* eosB = (int*)w;  w += N1_;
  int* pA   = (int*)w;  w += T_ * N1_;
  int* pB   = (int*)w;  w += T_ * N1_;

  // ---- prologue ----
  gemm_k<<<dim3(8, 1, 1), 256, 0, stream>>>(last_h + B_ * H_, W_init, nullptr, H_,
      b_init, nullptr, h, B_, H_, H_, H_, 0);
  gemm_k<<<dim3(8, 1, 1), 256, 0, stream>>>(last_c + B_ * H_, W_init, nullptr, H_,
      b_init, nullptr, c, B_, H_, H_, H_, 0);
  gemm_k<<<dim3(8, 128, 1), 256, 0, stream>>>(enc, We, nullptr, H_,
      nullptr, nullptr, encp, S_ * B_, H_, H_, H_, 0);

  for (int t = 0; t < T_; t++) {
    const int N = (t == 0) ? B_ : N1_;
    const int ntiles = (t == 0) ? 1 : 2;         // 64-row tiles for gts gemm
    const int nt32 = (t == 0) ? 1 : 3;           // 32-row tiles for logits gemm
    const int bdiv = (t == 0) ? 1 : K_;

    ppgemv_k<<<dim3(8, N), 256, 0, stream>>>(h, Wp, pp);
    score_k<<<dim3(8, N), 512, 0, stream>>>(pp, encp, Wv, mask, emb, tok, h,
        sc, xcat, bdiv, t == 0 ? 1 : 0);
    ctx_k<<<dim3(8, N), 256, 0, stream>>>(sc, enc, xcat, bdiv);
    gemm_k<<<dim3(32, ntiles, 4), 256, 0, stream>>>(xcat, W_ih, W_hh, E_ + H_,
        b_ih, b_hh, gts, N, 1280, 4 * H_, 320, GST);
    lstm_k<<<N, 256, 0, stream>>>(gts, c, xcat, h2, c2);
    lggemm_k<<<dim3(LG_MT, nt32), 512, 0, stream>>>(xcat, Wc, bc, N,
        ptv, pti, pmx, psm);
    lgmerge_k<<<N, 128, 0, stream>>>(ptv, pti, pmx, psm, rtv, rti, rmax, rlse);
    if (t == 0) {
      reorder0_k<<<N1_, 256, 0, stream>>>(h2, c2, h, c, rtv, rti, rmax, rlse,
          cumA, eosA, tok, pA);
    } else {
      float* cumOld = (t & 1) ? cumA : cumB;
      float* cumNew = (t & 1) ? cumB : cumA;
      int* eosOld = (t & 1) ? eosA : eosB;
      int* eosNew = (t & 1) ? eosB : eosA;
      int* pOld   = (t & 1) ? pA : pB;
      int* pNew   = (t & 1) ? pB : pA;
      reorder1_k<<<N1_, 256, 0, stream>>>(h2, c2, h, c, rtv, rti, rmax, rlse,
          cumOld, cumNew, eosOld, eosNew, pOld, pNew, tok, t);
    }
  }

  // t=31 odd -> preds in pB, cum in cumB
  finalout_k<<<5, 256, 0, stream>>>(pB, cumB, (float*)d_out);
}